// Round 12
// baseline (252.027 us; speedup 1.0000x reference)
//
#include <hip/hip_runtime.h>
#include <math.h>

typedef __bf16 bf16x8 __attribute__((ext_vector_type(8)));
typedef float  f32x4  __attribute__((ext_vector_type(4)));
typedef unsigned short u16x8 __attribute__((ext_vector_type(8)));

__device__ __forceinline__ float bf2f(unsigned short u) {
    return __uint_as_float(((unsigned int)u) << 16);
}
__device__ __forceinline__ unsigned short f2bf_n(float f) {
    return __builtin_bit_cast(unsigned short, (__bf16)f);  // native cvt (RNE)
}

// dims
#define BATCH 4
#define SEQ 512
#define DM 1024
#define NH 16
#define DH 64
#define DFF 4096
#define MROWS (BATCH * SEQ)   // 2048

__global__ __launch_bounds__(256) void fill0_kernel(float* __restrict__ out) {
    out[blockIdx.x * 256 + threadIdx.x] = 0.0f;
}

// ---------------- weight transpose+convert: in[K][N] f32 -> out[N][K] bf16 ----------
// 64(k) x 32(n) tiles; b128 writes
__global__ __launch_bounds__(256) void tconv_kernel(const float* __restrict__ in,
                                                    unsigned short* __restrict__ out,
                                                    int K, int N) {
    __shared__ float tile[64][33];
    const int n0 = blockIdx.x * 32, k0 = blockIdx.y * 64;
    const int t = threadIdx.x;
    const int tx = t & 31, ty = t >> 5;  // ty 0..7
    #pragma unroll
    for (int i = 0; i < 8; ++i)
        tile[ty + i * 8][tx] = in[(size_t)(k0 + ty + i * 8) * N + n0 + tx];
    __syncthreads();
    const int nr = t >> 3;          // 0..31
    const int ks = (t & 7) * 8;     // 0..56
    u16x8 v;
    #pragma unroll
    for (int j = 0; j < 8; ++j) v[j] = f2bf_n(tile[ks + j][nr]);
    *(u16x8*)&out[(size_t)(n0 + nr) * K + k0 + ks] = v;
}

// ---------------- 1) sinusoidal emb + silu ----------------
__global__ void semb_kernel(const int* __restrict__ ts, float* __restrict__ semb) {
    int b = blockIdx.x;
    float x = (float)ts[b] * 40.0f;
    for (int j = threadIdx.x; j < 1024; j += 256) {
        int idx = (j < 512) ? j : (j - 512);
        float fr = expf(-9.210340371976184f * (float)idx / 511.0f);
        float e = x * fr;
        float v = (j < 512) ? sinf(e) : cosf(e);
        semb[b * 1024 + j] = v / (1.0f + expf(-v));
    }
}

// ---------------- 2a) ada partials ----------------
__global__ __launch_bounds__(256) void ada_part_kernel(const float* __restrict__ semb,
                                                       const float* __restrict__ W,
                                                       float* __restrict__ part) {
    const int nb = blockIdx.x, kc = blockIdx.y;
    const int t = threadIdx.x;
    __shared__ float e_s[4][64];
    e_s[t >> 6][t & 63] = semb[(t >> 6) * 1024 + kc * 64 + (t & 63)];
    __syncthreads();
    const int n = nb * 128 + (t & 127);
    const int half = t >> 7;
    float a0 = 0.f, a1 = 0.f, a2 = 0.f, a3 = 0.f;
    const int kk0 = half * 32;
    #pragma unroll 8
    for (int kk = kk0; kk < kk0 + 32; ++kk) {
        const float w = W[(size_t)(kc * 64 + kk) * 2048 + n];
        a0 += e_s[0][kk] * w; a1 += e_s[1][kk] * w;
        a2 += e_s[2][kk] * w; a3 += e_s[3][kk] * w;
    }
    const int j = kc * 2 + half;
    float* p = part + (size_t)j * 4 * 2048 + n;
    p[0] = a0; p[2048] = a1; p[2 * 2048] = a2; p[3 * 2048] = a3;
}

// ---------------- 2b) ada reduce ----------------
__global__ __launch_bounds__(256) void ada_red_kernel(const float* __restrict__ part,
                                                      const float* __restrict__ bias,
                                                      float* __restrict__ ss) {
    const int idx = blockIdx.x * 256 + threadIdx.x;
    const int b = idx >> 11, n = idx & 2047;
    float acc = bias[n];
    #pragma unroll 8
    for (int j = 0; j < 32; ++j) acc += part[((size_t)j * 4 + b) * 2048 + n];
    ss[b * 2048 + n] = acc;
}

// ---------------- 3) AdaLN ----------------
__global__ __launch_bounds__(256) void adaln_kernel(const float* __restrict__ src,
                                                    const float* __restrict__ ss,
                                                    unsigned short* __restrict__ xb) {
    int r = blockIdx.x;
    int b = r >> 9;
    int t = threadIdx.x;
    float4 v4 = *reinterpret_cast<const float4*>(&src[(size_t)r * DM + t * 4]);
    float v[4] = {v4.x, v4.y, v4.z, v4.w};
    float s = v[0] + v[1] + v[2] + v[3];
    float q = v[0]*v[0] + v[1]*v[1] + v[2]*v[2] + v[3]*v[3];
    #pragma unroll
    for (int off = 32; off > 0; off >>= 1) { s += __shfl_down(s, off); q += __shfl_down(q, off); }
    __shared__ float red[8];
    if ((t & 63) == 0) { red[t >> 6] = s; red[4 + (t >> 6)] = q; }
    __syncthreads();
    s = red[0] + red[1] + red[2] + red[3];
    q = red[4] + red[5] + red[6] + red[7];
    float mean = s * (1.0f / DM);
    float var = q * (1.0f / DM) - mean * mean;
    float rstd = rsqrtf(var + 1e-5f);
    ushort4 o;
    o.x = f2bf_n((v[0]-mean)*rstd*(1.0f+ss[b*2048 + t*4+0]) + ss[b*2048+1024 + t*4+0]);
    o.y = f2bf_n((v[1]-mean)*rstd*(1.0f+ss[b*2048 + t*4+1]) + ss[b*2048+1024 + t*4+1]);
    o.z = f2bf_n((v[2]-mean)*rstd*(1.0f+ss[b*2048 + t*4+2]) + ss[b*2048+1024 + t*4+2]);
    o.w = f2bf_n((v[3]-mean)*rstd*(1.0f+ss[b*2048 + t*4+3]) + ss[b*2048+1024 + t*4+3]);
    *reinterpret_cast<ushort4*>(&xb[(size_t)r * DM + t * 4]) = o;
}

// ---------------- LN2 ----------------
__global__ __launch_bounds__(256) void ln2_kernel(const unsigned short* __restrict__ x,
                                                  const float* __restrict__ g2,
                                                  const float* __restrict__ beta2,
                                                  unsigned short* __restrict__ hout) {
    int r = blockIdx.x;
    int t = threadIdx.x;
    ushort4 s4 = *reinterpret_cast<const ushort4*>(&x[(size_t)r * DM + t * 4]);
    float v[4] = {bf2f(s4.x), bf2f(s4.y), bf2f(s4.z), bf2f(s4.w)};
    float s = v[0] + v[1] + v[2] + v[3];
    float q = v[0]*v[0] + v[1]*v[1] + v[2]*v[2] + v[3]*v[3];
    #pragma unroll
    for (int off = 32; off > 0; off >>= 1) { s += __shfl_down(s, off); q += __shfl_down(q, off); }
    __shared__ float red[8];
    if ((t & 63) == 0) { red[t >> 6] = s; red[4 + (t >> 6)] = q; }
    __syncthreads();
    s = red[0] + red[1] + red[2] + red[3];
    q = red[4] + red[5] + red[6] + red[7];
    float mean = s * (1.0f / DM);
    float var = q * (1.0f / DM) - mean * mean;
    float rstd = rsqrtf(var + 1e-5f);
    ushort4 o;
    o.x = f2bf_n((v[0]-mean)*rstd*g2[t*4+0] + beta2[t*4+0]);
    o.y = f2bf_n((v[1]-mean)*rstd*g2[t*4+1] + beta2[t*4+1]);
    o.z = f2bf_n((v[2]-mean)*rstd*g2[t*4+2] + beta2[t*4+2]);
    o.w = f2bf_n((v[3]-mean)*rstd*g2[t*4+3] + beta2[t*4+3]);
    *reinterpret_cast<ushort4*>(&hout[(size_t)r * DM + t * 4]) = o;
}

// ============ bf16-weight GEMM, double-buffered LDS, 1 barrier/k-tile ============
// MODE: 0 ->bf16; 1 +resid->bf16; 2 gelu2->bf16; 3 +bias+resid->f32; 4 accum->f32
#define TBM 64
#define TBN 128
#define TBK 64
#define PIT 72   // LDS row pitch (ushorts); 144B -> 2-way bank aliasing (free)

template<int MODE>
__global__ __launch_bounds__(256) void gemm_bt(
    const unsigned short* __restrict__ A,
    const unsigned short* __restrict__ Wta, const unsigned short* __restrict__ Wtb,
    const unsigned short* __restrict__ Wtc,
    const float* __restrict__ ba, const float* __restrict__ bbb, const float* __restrict__ bc,
    const unsigned short* __restrict__ resid,
    unsigned short* __restrict__ oa, unsigned short* __restrict__ ob,
    unsigned short* __restrict__ oc,
    float* __restrict__ outF,
    int M, int N, int K, int ldk)
{
    // bijective XCD-chunked swizzle (nwg % 8 == 0 for all our grids)
    const int gx = gridDim.x, gy = gridDim.y;
    const int nwg = gx * gy * gridDim.z;
    const int wid = blockIdx.x + gx * (blockIdx.y + gy * blockIdx.z);
    const int aid = (wid & 7) * (nwg >> 3) + (wid >> 3);
    const int bx = aid % gx;
    const int by = (aid / gx) % gy;
    const int sel = aid / (gx * gy);

    const unsigned short* Wt = (sel == 0) ? Wta : (sel == 1) ? Wtb : Wtc;
    const float* bias = (sel == 0) ? ba : (sel == 1) ? bbb : bc;
    unsigned short* outB = (sel == 0) ? oa : (sel == 1) ? ob : oc;

    __shared__ unsigned short As[2][TBM * PIT];   // 2 x 9 KB
    __shared__ unsigned short Bs[2][TBN * PIT];   // 2 x 18 KB
    const int t = threadIdx.x;
    const int lane = t & 63;
    const int w = t >> 6, wm = w >> 1, wn = w & 1;
    const int l15 = lane & 15, l4 = lane >> 4;
    const int m0 = by * TBM, n0 = bx * TBN;

    f32x4 acc[2][4];
    #pragma unroll
    for (int i = 0; i < 2; ++i)
        #pragma unroll
        for (int j = 0; j < 4; ++j)
            #pragma unroll
            for (int r = 0; r < 4; ++r) acc[i][j][r] = 0.0f;

    const int ar = t >> 2, aseg = (t & 3) * 16;
    const unsigned short* aG = A + (size_t)(m0 + ar) * K + aseg;
    const int aLo = ar * PIT + aseg;
    const int br = t >> 1, bseg = (t & 1) * 32;
    const unsigned short* bG = Wt + (size_t)(n0 + br) * ldk + bseg;
    const int bLo = br * PIT + bseg;

    // prologue: tile 0 -> buf 0
    u16x8 ra0 = *(const u16x8*)(aG);
    u16x8 ra1 = *(const u16x8*)(aG + 8);
    u16x8 rb0 = *(const u16x8*)(bG);
    u16x8 rb1 = *(const u16x8*)(bG + 8);
    u16x8 rb2 = *(const u16x8*)(bG + 16);
    u16x8 rb3 = *(const u16x8*)(bG + 24);
    *(u16x8*)&As[0][aLo] = ra0; *(u16x8*)&As[0][aLo + 8] = ra1;
    *(u16x8*)&Bs[0][bLo] = rb0; *(u16x8*)&Bs[0][bLo + 8] = rb1;
    *(u16x8*)&Bs[0][bLo + 16] = rb2; *(u16x8*)&Bs[0][bLo + 24] = rb3;
    __syncthreads();

    const int NT = K / TBK;
    for (int kt = 0; kt < NT; ++kt) {
        const int cur = kt & 1;
        const bool more = (kt + 1 < NT);
        if (more) {
            const int k0 = (kt + 1) * TBK;
            ra0 = *(const u16x8*)(aG + k0);
            ra1 = *(const u16x8*)(aG + k0 + 8);
            rb0 = *(const u16x8*)(bG + k0);
            rb1 = *(const u16x8*)(bG + k0 + 8);
            rb2 = *(const u16x8*)(bG + k0 + 16);
            rb3 = *(const u16x8*)(bG + k0 + 24);
        }
        #pragma unroll
        for (int kk = 0; kk < 2; ++kk) {
            bf16x8 af[2], bfr[4];
            #pragma unroll
            for (int mt = 0; mt < 2; ++mt) {
                u16x8 tmp = *(const u16x8*)&As[cur][(wm*32 + mt*16 + l15) * PIT + kk*32 + l4*8];
                af[mt] = __builtin_bit_cast(bf16x8, tmp);
            }
            #pragma unroll
            for (int nt = 0; nt < 4; ++nt) {
                u16x8 tmp = *(const u16x8*)&Bs[cur][(wn*64 + nt*16 + l15) * PIT + kk*32 + l4*8];
                bfr[nt] = __builtin_bit_cast(bf16x8, tmp);
            }
            #pragma unroll
            for (int mt = 0; mt < 2; ++mt)
                #pragma unroll
                for (int nt = 0; nt < 4; ++nt)
                    acc[mt][nt] = __builtin_amdgcn_mfma_f32_16x16x32_bf16(
                        af[mt], bfr[nt], acc[mt][nt], 0, 0, 0);
        }
        if (more) {
            const int nx = cur ^ 1;
            *(u16x8*)&As[nx][aLo] = ra0; *(u16x8*)&As[nx][aLo + 8] = ra1;
            *(u16x8*)&Bs[nx][bLo] = rb0; *(u16x8*)&Bs[nx][bLo + 8] = rb1;
            *(u16x8*)&Bs[nx][bLo + 16] = rb2; *(u16x8*)&Bs[nx][bLo + 24] = rb3;
            __syncthreads();
        }
    }

    #pragma unroll
    for (int mt = 0; mt < 2; ++mt) {
        const int mbase = m0 + wm*32 + mt*16 + l4*4;
        #pragma unroll
        for (int nt = 0; nt < 4; ++nt) {
            const int n = n0 + wn*64 + nt*16 + l15;
            const float bs = (MODE == 4) ? 0.0f : bias[n];
            #pragma unroll
            for (int r = 0; r < 4; ++r) {
                const int m = mbase + r;
                float v = acc[mt][nt][r] + bs;
                if (MODE == 2) v = v / (1.0f + expf(-1.702f * v));
                if (MODE == 1 || MODE == 3) v += bf2f(resid[(size_t)m * N + n]);
                if (MODE == 3)      outF[(size_t)m * N + n] = v;
                else if (MODE == 4) outF[(size_t)m * N + n] += v;
                else                outB[(size_t)m * N + n] = f2bf_n(v);
            }
        }
    }
}

// ---------------- MFMA flash attention: 32 q-rows, 2 waves, K-tiles of 64 ----------------
#define QB2 32
#define AKT 64
#define KROW 72
#define VROW 72
#define PROW 72

__global__ __launch_bounds__(128) void attn_mfma(const unsigned short* __restrict__ qbuf,
                                                 const unsigned short* __restrict__ kbuf,
                                                 const unsigned short* __restrict__ vbuf,
                                                 const float* __restrict__ attb,
                                                 const int* __restrict__ mask,
                                                 unsigned short* __restrict__ ctx) {
    __shared__ unsigned short Ks[AKT * KROW];      // 9216 B
    __shared__ unsigned short Vt[DH * VROW];       // 9216 B
    __shared__ unsigned short Pb[2 * 16 * PROW];   // 4608 B
    const int t = threadIdx.x;       // 0..127
    const int lane = t & 63;
    const int w = t >> 6;            // 0..1
    const int l15 = lane & 15, l4 = lane >> 4;
    const int q0 = blockIdx.x * QB2;
    const int h = blockIdx.y;
    const int b = blockIdx.z;

    bf16x8 qf[2];
    {
        const unsigned short* qrow = qbuf + ((size_t)(b * SEQ + q0 + w * 16 + l15)) * DM + h * DH;
        u16x8 t0 = *(const u16x8*)(qrow + l4 * 8);
        u16x8 t1 = *(const u16x8*)(qrow + 32 + l4 * 8);
        qf[0] = __builtin_bit_cast(bf16x8, t0);
        qf[1] = __builtin_bit_cast(bf16x8, t1);
    }

    float m[4] = {-1e30f, -1e30f, -1e30f, -1e30f};
    float l[4] = {0.0f, 0.0f, 0.0f, 0.0f};
    f32x4 o[4];
    #pragma unroll
    for (int dt = 0; dt < 4; ++dt)
        #pragma unroll
        for (int r = 0; r < 4; ++r) o[dt][r] = 0.0f;

    unsigned short* Pw = Pb + w * 16 * PROW;

    for (int kt = 0; kt < SEQ / AKT; ++kt) {   // 8 tiles of 64 keys
        const int kbase = kt * AKT;
        const float* bptr = attb + (((size_t)(b * NH + h)) * SEQ + (q0 + w * 16)) * SEQ + kbase;
        const int* mptr = mask + ((size_t)(b * SEQ) + q0 + w * 16) * SEQ + kbase;

        // bias folded into MFMA C-in (issued before staging)
        f32x4 acc[4];
        int mk[4][4];
        #pragma unroll
        for (int nt = 0; nt < 4; ++nt)
            #pragma unroll
            for (int r = 0; r < 4; ++r) {
                acc[nt][r] = 8.0f * bptr[(size_t)(l4 * 4 + r) * SEQ + nt * 16 + l15];
                mk[nt][r] = mptr[(size_t)(l4 * 4 + r) * SEQ + nt * 16 + l15];
            }

        __syncthreads();
        // stage K tile [64][64]
        {
            const int kr = t >> 1, c0 = (t & 1) * 32;
            const unsigned short* g = kbuf + ((size_t)(b * SEQ + kbase + kr)) * DM + h * DH + c0;
            u16x8 v0 = *(const u16x8*)(g);
            u16x8 v1 = *(const u16x8*)(g + 8);
            u16x8 v2 = *(const u16x8*)(g + 16);
            u16x8 v3 = *(const u16x8*)(g + 24);
            unsigned short* s = Ks + kr * KROW + c0;
            *(u16x8*)s = v0; *(u16x8*)(s + 8) = v1;
            *(u16x8*)(s + 16) = v2; *(u16x8*)(s + 24) = v3;
        }
        // stage V transposed: Vt[d][k] (packed u32: k even|odd)
        {
            const int kp = t & 31;
            unsigned int* vt32 = (unsigned int*)Vt;
            #pragma unroll
            for (int g8 = (t >> 5); g8 < 8; g8 += 4) {
                const unsigned short* ga =
                    vbuf + ((size_t)(b * SEQ + kbase + 2 * kp)) * DM + h * DH + g8 * 8;
                u16x8 va = *(const u16x8*)ga;
                u16x8 vb = *(const u16x8*)(ga + DM);
                #pragma unroll
                for (int j = 0; j < 8; ++j) {
                    const int d = g8 * 8 + j;
                    vt32[d * (VROW / 2) + kp] =
                        (unsigned int)va[j] | ((unsigned int)vb[j] << 16);
                }
            }
        }
        __syncthreads();

        #pragma unroll
        for (int kk = 0; kk < 2; ++kk) {
            #pragma unroll
            for (int nt = 0; nt < 4; ++nt) {
                u16x8 tmp = *(const u16x8*)(Ks + (nt * 16 + l15) * KROW + kk * 32 + l4 * 8);
                acc[nt] = __builtin_amdgcn_mfma_f32_16x16x32_bf16(
                    qf[kk], __builtin_bit_cast(bf16x8, tmp), acc[nt], 0, 0, 0);
            }
        }

        float pm[4] = {-1e30f, -1e30f, -1e30f, -1e30f};
        #pragma unroll
        for (int nt = 0; nt < 4; ++nt) {
            #pragma unroll
            for (int r = 0; r < 4; ++r) {
                float sv = acc[nt][r] * 0.125f;
                if (mk[nt][r]) sv = -1e30f;
                acc[nt][r] = sv;
                pm[r] = fmaxf(pm[r], sv);
            }
        }
        #pragma unroll
        for (int r = 0; r < 4; ++r) {
            #pragma unroll
            for (int off = 1; off < 16; off <<= 1)
                pm[r] = fmaxf(pm[r], __shfl_xor(pm[r], off));
        }
        float al[4], ps[4];
        #pragma unroll
        for (int r = 0; r < 4; ++r) {
            const float mn = fmaxf(m[r], pm[r]);
            al[r] = __expf(m[r] - mn);
            m[r] = mn;
            ps[r] = 0.0f;
        }
        #pragma unroll
        for (int nt = 0; nt < 4; ++nt) {
            #pragma unroll
            for (int r = 0; r < 4; ++r) {
                const float p = __expf(acc[nt][r] - m[r]);
                acc[nt][r] = p;
                ps[r] += p;
            }
        }
        #pragma unroll
        for (int r = 0; r < 4; ++r) {
            #pragma unroll
            for (int off = 1; off < 16; off <<= 1) ps[r] += __shfl_xor(ps[r], off);
            l[r] = l[r] * al[r] + ps[r];
        }
        #pragma unroll
        for (int dt = 0; dt < 4; ++dt)
            #pragma unroll
            for (int r = 0; r < 4; ++r) o[dt][r] *= al[r];

        #pragma unroll
        for (int nt = 0; nt < 4; ++nt)
            #pragma unroll
            for (int r = 0; r < 4; ++r)
                Pw[(l4 * 4 + r) * PROW + nt * 16 + l15] = f2bf_n(acc[nt][r]);

        #pragma unroll
        for (int ks = 0; ks < 2; ++ks) {
            u16x8 pa = *(const u16x8*)(Pw + l15 * PROW + ks * 32 + l4 * 8);
            #pragma unroll
            for (int dt = 0; dt < 4; ++dt) {
                u16x8 vv = *(const u16x8*)(Vt + (dt * 16 + l15) * VROW + ks * 32 + l4 * 8);
                o[dt] = __builtin_amdgcn_mfma_f32_16x16x32_bf16(
                    __builtin_bit_cast(bf16x8, pa), __builtin_bit_cast(bf16x8, vv),
                    o[dt], 0, 0, 0);
            }
        }
    }

    #pragma unroll
    for (int r = 0; r < 4; ++r) {
        const float inv = 1.0f / l[r];
        const size_t row = (size_t)(b * SEQ + q0 + w * 16 + l4 * 4 + r) * DM + h * DH;
        #pragma unroll
        for (int dt = 0; dt < 4; ++dt)
            ctx[row + dt * 16 + l15] = f2bf_n(o[dt][r] * inv);
    }
}

// ---------------- host launch ----------------
extern "C" void kernel_launch(void* const* d_in, const int* in_sizes, int n_in,
                              void* d_out, int out_size, void* d_ws, size_t ws_size,
                              hipStream_t stream) {
    const float* src  = (const float*)d_in[0];
    const int*   mask = (const int*)d_in[1];
    const int*   ts   = (const int*)d_in[2];
    const float* attb = (const float*)d_in[3];
    const float* Wada = (const float*)d_in[4];
    const float* bada = (const float*)d_in[5];
    const float* Wq   = (const float*)d_in[6];
    const float* bq   = (const float*)d_in[7];
    const float* Wk   = (const float*)d_in[8];
    const float* bk   = (const float*)d_in[9];
    const float* Wv   = (const float*)d_in[10];
    const float* bv   = (const float*)d_in[11];
    const float* Wo   = (const float*)d_in[12];
    const float* bo   = (const float*)d_in[13];
    const float* W1   = (const float*)d_in[14];
    const float* b1   = (const float*)d_in[15];
    const float* W2   = (const float*)d_in[16];
    const float* b2   = (const float*)d_in[17];
    const float* g2   = (const float*)d_in[18];
    const float* bt2  = (const float*)d_in[19];
    float* out = (float*)d_out;

    const size_t MB = 1024 * 1024;
    const size_t NEED = 65536 + 36 * MB;  // proven available in round 11
    if (ws_size < NEED) {
        fill0_kernel<<<(size_t)MROWS * DM / 256, 256, 0, stream>>>(out);
        return;
    }

    char* ws = (char*)d_ws;
    float* semb = (float*)(ws + 4096);
    float* ss   = (float*)(ws + 24576);
    char*  base = ws + 65536;
    unsigned short* slotA = (unsigned short*)(base);            // xb -> mid
    unsigned short* slotB = (unsigned short*)(base + 4 * MB);   // qb -> x2
    unsigned short* slotC = (unsigned short*)(base + 8 * MB);   // kb -> h
    unsigned short* vb   = (unsigned short*)d_out;
    unsigned short* ctxb = (unsigned short*)((char*)d_out + 4 * MB);
    unsigned short* xb = slotA;
    unsigned short* qb = slotB;
    unsigned short* kb = slotC;
    unsigned short* x2 = slotB;
    unsigned short* hb = slotC;
    unsigned short* mid = slotA;
    float* adap = (float*)slotC;

    unsigned short* Wtq = (unsigned short*)(base + 12 * MB);
    unsigned short* Wtk = Wtq + 1024 * 1024;
    unsigned short* Wtv = Wtk + 1024 * 1024;
    unsigned short* Wto = Wtv + 1024 * 1024;
    unsigned short* Wt1 = Wto + 1024 * 1024;               // [4096][1024]
    unsigned short* Wt2 = Wt1 + (size_t)4096 * 1024;       // [1024][4096]

    tconv_kernel<<<dim3(32, 16), 256, 0, stream>>>(Wq, Wtq, 1024, 1024);
    tconv_kernel<<<dim3(32, 16), 256, 0, stream>>>(Wk, Wtk, 1024, 1024);
    tconv_kernel<<<dim3(32, 16), 256, 0, stream>>>(Wv, Wtv, 1024, 1024);
    tconv_kernel<<<dim3(32, 16), 256, 0, stream>>>(Wo, Wto, 1024, 1024);
    tconv_kernel<<<dim3(128, 16), 256, 0, stream>>>(W1, Wt1, 1024, 4096);
    tconv_kernel<<<dim3(32, 64), 256, 0, stream>>>(W2, Wt2, 4096, 1024);

    semb_kernel<<<4, 256, 0, stream>>>(ts, semb);
    ada_part_kernel<<<dim3(16, 16), 256, 0, stream>>>(semb, Wada, adap);
    ada_red_kernel<<<32, 256, 0, stream>>>(adap, bada, ss);
    adaln_kernel<<<MROWS, 256, 0, stream>>>(src, ss, xb);

    gemm_bt<0><<<dim3(8, 32, 3), 256, 0, stream>>>(xb, Wtq, Wtk, Wtv, bq, bk, bv, nullptr,
                                                   qb, kb, vb, nullptr, MROWS, DM, DM, DM);
    attn_mfma<<<dim3(SEQ / QB2, NH, BATCH), 128, 0, stream>>>(qb, kb, vb, attb, mask, ctxb);
    gemm_bt<1><<<dim3(8, 32), 256, 0, stream>>>(ctxb, Wto, Wto, Wto, bo, bo, bo, xb,
                                                x2, x2, x2, nullptr, MROWS, DM, DM, DM);
    ln2_kernel<<<MROWS, 256, 0, stream>>>(x2, g2, bt2, hb);
    for (int nc = 0; nc < 4; ++nc) {
        const unsigned short* w1c = Wt1 + (size_t)nc * 1024 * 1024;
        const float* b1c = b1 + nc * 1024;
        gemm_bt<2><<<dim3(8, 32), 256, 0, stream>>>(hb, w1c, w1c, w1c, b1c, b1c, b1c,
                                                    nullptr, mid, mid, mid, nullptr,
                                                    MROWS, DM, DM, DM);
        const unsigned short* w2c = Wt2 + nc * 1024;
        if (nc == 0)
            gemm_bt<3><<<dim3(8, 32), 256, 0, stream>>>(mid, w2c, w2c, w2c, b2, b2, b2,
                                                        x2, nullptr, nullptr, nullptr, out,
                                                        MROWS, DM, DM, DFF);
        else
            gemm_bt<4><<<dim3(8, 32), 256, 0, stream>>>(mid, w2c, w2c, w2c,
                                                        nullptr, nullptr, nullptr, nullptr,
                                                        nullptr, nullptr, nullptr, out,
                                                        MROWS, DM, DM, DFF);
    }
}

// Round 13
// 245.222 us; speedup vs baseline: 1.0278x; 1.0278x over previous
//
#include <hip/hip_runtime.h>
#include <math.h>

typedef __bf16 bf16x8 __attribute__((ext_vector_type(8)));
typedef float  f32x4  __attribute__((ext_vector_type(4)));
typedef unsigned short u16x8 __attribute__((ext_vector_type(8)));

__device__ __forceinline__ float bf2f(unsigned short u) {
    return __uint_as_float(((unsigned int)u) << 16);
}
__device__ __forceinline__ unsigned short f2bf_n(float f) {
    return __builtin_bit_cast(unsigned short, (__bf16)f);  // native cvt (RNE)
}

// dims
#define BATCH 4
#define SEQ 512
#define DM 1024
#define NH 16
#define DH 64
#define DFF 4096
#define MROWS (BATCH * SEQ)   // 2048

__global__ __launch_bounds__(256) void fill0_kernel(float* __restrict__ out) {
    out[blockIdx.x * 256 + threadIdx.x] = 0.0f;
}

// ---------------- weight transpose+convert: in[K][N] f32 -> out[N][K] bf16 ----------
__global__ __launch_bounds__(256) void tconv_kernel(const float* __restrict__ in,
                                                    unsigned short* __restrict__ out,
                                                    int K, int N) {
    __shared__ float tile[64][33];
    const int n0 = blockIdx.x * 32, k0 = blockIdx.y * 64;
    const int t = threadIdx.x;
    const int tx = t & 31, ty = t >> 5;
    #pragma unroll
    for (int i = 0; i < 8; ++i)
        tile[ty + i * 8][tx] = in[(size_t)(k0 + ty + i * 8) * N + n0 + tx];
    __syncthreads();
    const int nr = t >> 3;
    const int ks = (t & 7) * 8;
    u16x8 v;
    #pragma unroll
    for (int j = 0; j < 8; ++j) v[j] = f2bf_n(tile[ks + j][nr]);
    *(u16x8*)&out[(size_t)(n0 + nr) * K + k0 + ks] = v;
}

// fused 4x (1024x1024) transpose
__global__ __launch_bounds__(256) void tconv4_kernel(const float* __restrict__ i0,
                                                     const float* __restrict__ i1,
                                                     const float* __restrict__ i2,
                                                     const float* __restrict__ i3,
                                                     unsigned short* __restrict__ o0,
                                                     unsigned short* __restrict__ o1,
                                                     unsigned short* __restrict__ o2,
                                                     unsigned short* __restrict__ o3) {
    const int z = blockIdx.z;
    const float* in = (z == 0) ? i0 : (z == 1) ? i1 : (z == 2) ? i2 : i3;
    unsigned short* out = (z == 0) ? o0 : (z == 1) ? o1 : (z == 2) ? o2 : o3;
    __shared__ float tile[64][33];
    const int n0 = blockIdx.x * 32, k0 = blockIdx.y * 64;
    const int t = threadIdx.x;
    const int tx = t & 31, ty = t >> 5;
    #pragma unroll
    for (int i = 0; i < 8; ++i)
        tile[ty + i * 8][tx] = in[(size_t)(k0 + ty + i * 8) * 1024 + n0 + tx];
    __syncthreads();
    const int nr = t >> 3;
    const int ks = (t & 7) * 8;
    u16x8 v;
    #pragma unroll
    for (int j = 0; j < 8; ++j) v[j] = f2bf_n(tile[ks + j][nr]);
    *(u16x8*)&out[(size_t)(n0 + nr) * 1024 + k0 + ks] = v;
}

// ---------------- 1) sinusoidal emb + silu ----------------
__global__ void semb_kernel(const int* __restrict__ ts, float* __restrict__ semb) {
    int b = blockIdx.x;
    float x = (float)ts[b] * 40.0f;
    for (int j = threadIdx.x; j < 1024; j += 256) {
        int idx = (j < 512) ? j : (j - 512);
        float fr = expf(-9.210340371976184f * (float)idx / 511.0f);
        float e = x * fr;
        float v = (j < 512) ? sinf(e) : cosf(e);
        semb[b * 1024 + j] = v / (1.0f + expf(-v));
    }
}

// ---------------- 2a) ada partials ----------------
__global__ __launch_bounds__(256) void ada_part_kernel(const float* __restrict__ semb,
                                                       const float* __restrict__ W,
                                                       float* __restrict__ part) {
    const int nb = blockIdx.x, kc = blockIdx.y;
    const int t = threadIdx.x;
    __shared__ float e_s[4][64];
    e_s[t >> 6][t & 63] = semb[(t >> 6) * 1024 + kc * 64 + (t & 63)];
    __syncthreads();
    const int n = nb * 128 + (t & 127);
    const int half = t >> 7;
    float a0 = 0.f, a1 = 0.f, a2 = 0.f, a3 = 0.f;
    const int kk0 = half * 32;
    #pragma unroll 8
    for (int kk = kk0; kk < kk0 + 32; ++kk) {
        const float w = W[(size_t)(kc * 64 + kk) * 2048 + n];
        a0 += e_s[0][kk] * w; a1 += e_s[1][kk] * w;
        a2 += e_s[2][kk] * w; a3 += e_s[3][kk] * w;
    }
    const int j = kc * 2 + half;
    float* p = part + (size_t)j * 4 * 2048 + n;
    p[0] = a0; p[2048] = a1; p[2 * 2048] = a2; p[3 * 2048] = a3;
}

// ---------------- 2b) ada reduce ----------------
__global__ __launch_bounds__(256) void ada_red_kernel(const float* __restrict__ part,
                                                      const float* __restrict__ bias,
                                                      float* __restrict__ ss) {
    const int idx = blockIdx.x * 256 + threadIdx.x;
    const int b = idx >> 11, n = idx & 2047;
    float acc = bias[n];
    #pragma unroll 8
    for (int j = 0; j < 32; ++j) acc += part[((size_t)j * 4 + b) * 2048 + n];
    ss[b * 2048 + n] = acc;
}

// ---------------- 3) AdaLN ----------------
__global__ __launch_bounds__(256) void adaln_kernel(const float* __restrict__ src,
                                                    const float* __restrict__ ss,
                                                    unsigned short* __restrict__ xb) {
    int r = blockIdx.x;
    int b = r >> 9;
    int t = threadIdx.x;
    float4 v4 = *reinterpret_cast<const float4*>(&src[(size_t)r * DM + t * 4]);
    float v[4] = {v4.x, v4.y, v4.z, v4.w};
    float s = v[0] + v[1] + v[2] + v[3];
    float q = v[0]*v[0] + v[1]*v[1] + v[2]*v[2] + v[3]*v[3];
    #pragma unroll
    for (int off = 32; off > 0; off >>= 1) { s += __shfl_down(s, off); q += __shfl_down(q, off); }
    __shared__ float red[8];
    if ((t & 63) == 0) { red[t >> 6] = s; red[4 + (t >> 6)] = q; }
    __syncthreads();
    s = red[0] + red[1] + red[2] + red[3];
    q = red[4] + red[5] + red[6] + red[7];
    float mean = s * (1.0f / DM);
    float var = q * (1.0f / DM) - mean * mean;
    float rstd = rsqrtf(var + 1e-5f);
    ushort4 o;
    o.x = f2bf_n((v[0]-mean)*rstd*(1.0f+ss[b*2048 + t*4+0]) + ss[b*2048+1024 + t*4+0]);
    o.y = f2bf_n((v[1]-mean)*rstd*(1.0f+ss[b*2048 + t*4+1]) + ss[b*2048+1024 + t*4+1]);
    o.z = f2bf_n((v[2]-mean)*rstd*(1.0f+ss[b*2048 + t*4+2]) + ss[b*2048+1024 + t*4+2]);
    o.w = f2bf_n((v[3]-mean)*rstd*(1.0f+ss[b*2048 + t*4+3]) + ss[b*2048+1024 + t*4+3]);
    *reinterpret_cast<ushort4*>(&xb[(size_t)r * DM + t * 4]) = o;
}

// ---------------- LN2 ----------------
__global__ __launch_bounds__(256) void ln2_kernel(const unsigned short* __restrict__ x,
                                                  const float* __restrict__ g2,
                                                  const float* __restrict__ beta2,
                                                  unsigned short* __restrict__ hout) {
    int r = blockIdx.x;
    int t = threadIdx.x;
    ushort4 s4 = *reinterpret_cast<const ushort4*>(&x[(size_t)r * DM + t * 4]);
    float v[4] = {bf2f(s4.x), bf2f(s4.y), bf2f(s4.z), bf2f(s4.w)};
    float s = v[0] + v[1] + v[2] + v[3];
    float q = v[0]*v[0] + v[1]*v[1] + v[2]*v[2] + v[3]*v[3];
    #pragma unroll
    for (int off = 32; off > 0; off >>= 1) { s += __shfl_down(s, off); q += __shfl_down(q, off); }
    __shared__ float red[8];
    if ((t & 63) == 0) { red[t >> 6] = s; red[4 + (t >> 6)] = q; }
    __syncthreads();
    s = red[0] + red[1] + red[2] + red[3];
    q = red[4] + red[5] + red[6] + red[7];
    float mean = s * (1.0f / DM);
    float var = q * (1.0f / DM) - mean * mean;
    float rstd = rsqrtf(var + 1e-5f);
    ushort4 o;
    o.x = f2bf_n((v[0]-mean)*rstd*g2[t*4+0] + beta2[t*4+0]);
    o.y = f2bf_n((v[1]-mean)*rstd*g2[t*4+1] + beta2[t*4+1]);
    o.z = f2bf_n((v[2]-mean)*rstd*g2[t*4+2] + beta2[t*4+2]);
    o.w = f2bf_n((v[3]-mean)*rstd*g2[t*4+3] + beta2[t*4+3]);
    *reinterpret_cast<ushort4*>(&hout[(size_t)r * DM + t * 4]) = o;
}

// ============ bf16-weight GEMM (round-12, verified) ============
#define TBM 64
#define TBN 128
#define TBK 64
#define PIT 72

template<int MODE>
__global__ __launch_bounds__(256) void gemm_bt(
    const unsigned short* __restrict__ A,
    const unsigned short* __restrict__ Wta, const unsigned short* __restrict__ Wtb,
    const unsigned short* __restrict__ Wtc,
    const float* __restrict__ ba, const float* __restrict__ bbb, const float* __restrict__ bc,
    const unsigned short* __restrict__ resid,
    unsigned short* __restrict__ oa, unsigned short* __restrict__ ob,
    unsigned short* __restrict__ oc,
    float* __restrict__ outF,
    int M, int N, int K, int ldk)
{
    const int gx = gridDim.x, gy = gridDim.y;
    const int nwg = gx * gy * gridDim.z;
    const int wid = blockIdx.x + gx * (blockIdx.y + gy * blockIdx.z);
    const int aid = (wid & 7) * (nwg >> 3) + (wid >> 3);
    const int bx = aid % gx;
    const int by = (aid / gx) % gy;
    const int sel = aid / (gx * gy);

    const unsigned short* Wt = (sel == 0) ? Wta : (sel == 1) ? Wtb : Wtc;
    const float* bias = (sel == 0) ? ba : (sel == 1) ? bbb : bc;
    unsigned short* outB = (sel == 0) ? oa : (sel == 1) ? ob : oc;

    __shared__ unsigned short As[2][TBM * PIT];
    __shared__ unsigned short Bs[2][TBN * PIT];
    const int t = threadIdx.x;
    const int lane = t & 63;
    const int w = t >> 6, wm = w >> 1, wn = w & 1;
    const int l15 = lane & 15, l4 = lane >> 4;
    const int m0 = by * TBM, n0 = bx * TBN;

    f32x4 acc[2][4];
    #pragma unroll
    for (int i = 0; i < 2; ++i)
        #pragma unroll
        for (int j = 0; j < 4; ++j)
            #pragma unroll
            for (int r = 0; r < 4; ++r) acc[i][j][r] = 0.0f;

    const int ar = t >> 2, aseg = (t & 3) * 16;
    const unsigned short* aG = A + (size_t)(m0 + ar) * K + aseg;
    const int aLo = ar * PIT + aseg;
    const int br = t >> 1, bseg = (t & 1) * 32;
    const unsigned short* bG = Wt + (size_t)(n0 + br) * ldk + bseg;
    const int bLo = br * PIT + bseg;

    u16x8 ra0 = *(const u16x8*)(aG);
    u16x8 ra1 = *(const u16x8*)(aG + 8);
    u16x8 rb0 = *(const u16x8*)(bG);
    u16x8 rb1 = *(const u16x8*)(bG + 8);
    u16x8 rb2 = *(const u16x8*)(bG + 16);
    u16x8 rb3 = *(const u16x8*)(bG + 24);
    *(u16x8*)&As[0][aLo] = ra0; *(u16x8*)&As[0][aLo + 8] = ra1;
    *(u16x8*)&Bs[0][bLo] = rb0; *(u16x8*)&Bs[0][bLo + 8] = rb1;
    *(u16x8*)&Bs[0][bLo + 16] = rb2; *(u16x8*)&Bs[0][bLo + 24] = rb3;
    __syncthreads();

    const int NT = K / TBK;
    for (int kt = 0; kt < NT; ++kt) {
        const int cur = kt & 1;
        const bool more = (kt + 1 < NT);
        if (more) {
            const int k0 = (kt + 1) * TBK;
            ra0 = *(const u16x8*)(aG + k0);
            ra1 = *(const u16x8*)(aG + k0 + 8);
            rb0 = *(const u16x8*)(bG + k0);
            rb1 = *(const u16x8*)(bG + k0 + 8);
            rb2 = *(const u16x8*)(bG + k0 + 16);
            rb3 = *(const u16x8*)(bG + k0 + 24);
        }
        #pragma unroll
        for (int kk = 0; kk < 2; ++kk) {
            bf16x8 af[2], bfr[4];
            #pragma unroll
            for (int mt = 0; mt < 2; ++mt) {
                u16x8 tmp = *(const u16x8*)&As[cur][(wm*32 + mt*16 + l15) * PIT + kk*32 + l4*8];
                af[mt] = __builtin_bit_cast(bf16x8, tmp);
            }
            #pragma unroll
            for (int nt = 0; nt < 4; ++nt) {
                u16x8 tmp = *(const u16x8*)&Bs[cur][(wn*64 + nt*16 + l15) * PIT + kk*32 + l4*8];
                bfr[nt] = __builtin_bit_cast(bf16x8, tmp);
            }
            #pragma unroll
            for (int mt = 0; mt < 2; ++mt)
                #pragma unroll
                for (int nt = 0; nt < 4; ++nt)
                    acc[mt][nt] = __builtin_amdgcn_mfma_f32_16x16x32_bf16(
                        af[mt], bfr[nt], acc[mt][nt], 0, 0, 0);
        }
        if (more) {
            const int nx = cur ^ 1;
            *(u16x8*)&As[nx][aLo] = ra0; *(u16x8*)&As[nx][aLo + 8] = ra1;
            *(u16x8*)&Bs[nx][bLo] = rb0; *(u16x8*)&Bs[nx][bLo + 8] = rb1;
            *(u16x8*)&Bs[nx][bLo + 16] = rb2; *(u16x8*)&Bs[nx][bLo + 24] = rb3;
            __syncthreads();
        }
    }

    #pragma unroll
    for (int mt = 0; mt < 2; ++mt) {
        const int mbase = m0 + wm*32 + mt*16 + l4*4;
        #pragma unroll
        for (int nt = 0; nt < 4; ++nt) {
            const int n = n0 + wn*64 + nt*16 + l15;
            const float bs = (MODE == 4) ? 0.0f : bias[n];
            #pragma unroll
            for (int r = 0; r < 4; ++r) {
                const int m = mbase + r;
                float v = acc[mt][nt][r] + bs;
                if (MODE == 2) v = v / (1.0f + expf(-1.702f * v));
                if (MODE == 1 || MODE == 3) v += bf2f(resid[(size_t)m * N + n]);
                if (MODE == 3)      outF[(size_t)m * N + n] = v;
                else if (MODE == 4) outF[(size_t)m * N + n] += v;
                else                outB[(size_t)m * N + n] = f2bf_n(v);
            }
        }
    }
}

// ---------- MFMA flash attention: vectorized bias+mask via LDS, reg prefetch ----------
#define QB2 32
#define AKT 64
#define KROW 72
#define VROW 72
#define PROW 72
#define SBPIT 80   // f32 pitch for combined bias/mask tile

__global__ __launch_bounds__(128) void attn_mfma(const unsigned short* __restrict__ qbuf,
                                                 const unsigned short* __restrict__ kbuf,
                                                 const unsigned short* __restrict__ vbuf,
                                                 const float* __restrict__ attb,
                                                 const int* __restrict__ mask,
                                                 unsigned short* __restrict__ ctx) {
    __shared__ unsigned short Ks[AKT * KROW];      // 9216 B
    __shared__ unsigned short Vt[DH * VROW];       // 9216 B
    __shared__ unsigned short Pb[2 * 16 * PROW];   // 4608 B
    __shared__ float Sb[QB2 * SBPIT];              // 10240 B
    const int t = threadIdx.x;       // 0..127
    const int lane = t & 63;
    const int w = t >> 6;
    const int l15 = lane & 15, l4 = lane >> 4;
    const int q0 = blockIdx.x * QB2;
    const int h = blockIdx.y;
    const int b = blockIdx.z;

    bf16x8 qf[2];
    {
        const unsigned short* qrow = qbuf + ((size_t)(b * SEQ + q0 + w * 16 + l15)) * DM + h * DH;
        u16x8 t0 = *(const u16x8*)(qrow + l4 * 8);
        u16x8 t1 = *(const u16x8*)(qrow + 32 + l4 * 8);
        qf[0] = __builtin_bit_cast(bf16x8, t0);
        qf[1] = __builtin_bit_cast(bf16x8, t1);
    }

    float m[4] = {-1e30f, -1e30f, -1e30f, -1e30f};
    float l[4] = {0.0f, 0.0f, 0.0f, 0.0f};
    f32x4 o[4];
    #pragma unroll
    for (int dt = 0; dt < 4; ++dt)
        #pragma unroll
        for (int r = 0; r < 4; ++r) o[dt][r] = 0.0f;

    unsigned short* Pw = Pb + w * 16 * PROW;

    // staging maps
    const int kr = t >> 1, c0 = (t & 1) * 32;      // K: row, col-half
    const int kp = t & 31, vg = t >> 5;            // V: key-pair, d-group base (0..3)

    u16x8 rk0, rk1, rk2, rk3, rv0, rv1, rv2, rv3;
    float4 rb[4];
    int4   rm[4];

#define LOADT(KT) {                                                                     \
    const int kbase = (KT) * AKT;                                                       \
    const unsigned short* gk = kbuf + ((size_t)(b * SEQ + kbase + kr)) * DM + h * DH + c0; \
    rk0 = *(const u16x8*)gk;        rk1 = *(const u16x8*)(gk + 8);                      \
    rk2 = *(const u16x8*)(gk + 16); rk3 = *(const u16x8*)(gk + 24);                     \
    const unsigned short* gv = vbuf + ((size_t)(b * SEQ + kbase + 2 * kp)) * DM + h * DH + vg * 8; \
    rv0 = *(const u16x8*)gv;        rv1 = *(const u16x8*)(gv + DM);                     \
    rv2 = *(const u16x8*)(gv + 32); rv3 = *(const u16x8*)(gv + DM + 32);                \
    const float* bp = attb + (((size_t)(b * NH + h)) * SEQ + (q0 + w * 16)) * SEQ + kbase; \
    const int* mp = mask + ((size_t)(b * SEQ) + q0 + w * 16) * SEQ + kbase;             \
    _Pragma("unroll")                                                                   \
    for (int i = 0; i < 4; ++i) {                                                       \
        const int e = lane + i * 64; const int row = e >> 4, cg = e & 15;               \
        rb[i] = *(const float4*)&bp[(size_t)row * SEQ + cg * 4];                        \
        rm[i] = *(const int4*)&mp[(size_t)row * SEQ + cg * 4];                          \
    } }

#define STORET() {                                                                      \
    unsigned short* s = Ks + kr * KROW + c0;                                            \
    *(u16x8*)s = rk0; *(u16x8*)(s + 8) = rk1;                                           \
    *(u16x8*)(s + 16) = rk2; *(u16x8*)(s + 24) = rk3;                                   \
    unsigned int* vt32 = (unsigned int*)Vt;                                             \
    _Pragma("unroll")                                                                   \
    for (int j = 0; j < 8; ++j) {                                                       \
        vt32[(vg * 8 + j) * (VROW / 2) + kp] =                                          \
            (unsigned int)rv0[j] | ((unsigned int)rv1[j] << 16);                        \
        vt32[((vg + 4) * 8 + j) * (VROW / 2) + kp] =                                    \
            (unsigned int)rv2[j] | ((unsigned int)rv3[j] << 16);                        \
    }                                                                                   \
    _Pragma("unroll")                                                                   \
    for (int i = 0; i < 4; ++i) {                                                       \
        const int e = lane + i * 64; const int row = e >> 4, cg = e & 15;               \
        float4 cc;                                                                      \
        cc.x = rm[i].x ? -8e30f : 8.0f * rb[i].x;                                       \
        cc.y = rm[i].y ? -8e30f : 8.0f * rb[i].y;                                       \
        cc.z = rm[i].z ? -8e30f : 8.0f * rb[i].z;                                       \
        cc.w = rm[i].w ? -8e30f : 8.0f * rb[i].w;                                       \
        *(float4*)&Sb[(w * 16 + row) * SBPIT + cg * 4] = cc;                            \
    } }

    LOADT(0);
    for (int kt = 0; kt < SEQ / AKT; ++kt) {
        __syncthreads();          // prior tile's LDS reads complete
        STORET();
        __syncthreads();
        if (kt + 1 < SEQ / AKT) LOADT(kt + 1);   // prefetch next tile under compute

        // acc init = combined bias/mask (C-in of QK MFMA)
        f32x4 acc[4];
        #pragma unroll
        for (int nt = 0; nt < 4; ++nt)
            #pragma unroll
            for (int r = 0; r < 4; ++r)
                acc[nt][r] = Sb[(w * 16 + l4 * 4 + r) * SBPIT + nt * 16 + l15];

        #pragma unroll
        for (int kk = 0; kk < 2; ++kk) {
            #pragma unroll
            for (int nt = 0; nt < 4; ++nt) {
                u16x8 tmp = *(const u16x8*)(Ks + (nt * 16 + l15) * KROW + kk * 32 + l4 * 8);
                acc[nt] = __builtin_amdgcn_mfma_f32_16x16x32_bf16(
                    qf[kk], __builtin_bit_cast(bf16x8, tmp), acc[nt], 0, 0, 0);
            }
        }

        float pm[4] = {-1e30f, -1e30f, -1e30f, -1e30f};
        #pragma unroll
        for (int nt = 0; nt < 4; ++nt) {
            #pragma unroll
            for (int r = 0; r < 4; ++r) {
                const float sv = acc[nt][r] * 0.125f;   // masked entries ≈ -1e30
                acc[nt][r] = sv;
                pm[r] = fmaxf(pm[r], sv);
            }
        }
        #pragma unroll
        for (int r = 0; r < 4; ++r) {
            #pragma unroll
            for (int off = 1; off < 16; off <<= 1)
                pm[r] = fmaxf(pm[r], __shfl_xor(pm[r], off));
        }
        float al[4], ps[4];
        #pragma unroll
        for (int r = 0; r < 4; ++r) {
            const float mn = fmaxf(m[r], pm[r]);
            al[r] = __expf(m[r] - mn);
            m[r] = mn;
            ps[r] = 0.0f;
        }
        #pragma unroll
        for (int nt = 0; nt < 4; ++nt) {
            #pragma unroll
            for (int r = 0; r < 4; ++r) {
                const float p = __expf(acc[nt][r] - m[r]);
                acc[nt][r] = p;
                ps[r] += p;
            }
        }
        #pragma unroll
        for (int r = 0; r < 4; ++r) {
            #pragma unroll
            for (int off = 1; off < 16; off <<= 1) ps[r] += __shfl_xor(ps[r], off);
            l[r] = l[r] * al[r] + ps[r];
        }
        #pragma unroll
        for (int dt = 0; dt < 4; ++dt)
            #pragma unroll
            for (int r = 0; r < 4; ++r) o[dt][r] *= al[r];

        #pragma unroll
        for (int nt = 0; nt < 4; ++nt)
            #pragma unroll
            for (int r = 0; r < 4; ++r)
                Pw[(l4 * 4 + r) * PROW + nt * 16 + l15] = f2bf_n(acc[nt][r]);

        #pragma unroll
        for (int ks = 0; ks < 2; ++ks) {
            u16x8 pa = *(const u16x8*)(Pw + l15 * PROW + ks * 32 + l4 * 8);
            #pragma unroll
            for (int dt = 0; dt < 4; ++dt) {
                u16x8 vv = *(const u16x8*)(Vt + (dt * 16 + l15) * VROW + ks * 32 + l4 * 8);
                o[dt] = __builtin_amdgcn_mfma_f32_16x16x32_bf16(
                    __builtin_bit_cast(bf16x8, pa), __builtin_bit_cast(bf16x8, vv),
                    o[dt], 0, 0, 0);
            }
        }
    }

    #pragma unroll
    for (int r = 0; r < 4; ++r) {
        const float inv = 1.0f / l[r];
        const size_t row = (size_t)(b * SEQ + q0 + w * 16 + l4 * 4 + r) * DM + h * DH;
        #pragma unroll
        for (int dt = 0; dt < 4; ++dt)
            ctx[row + dt * 16 + l15] = f2bf_n(o[dt][r] * inv);
    }
#undef LOADT
#undef STORET
}

// ---------------- host launch ----------------
extern "C" void kernel_launch(void* const* d_in, const int* in_sizes, int n_in,
                              void* d_out, int out_size, void* d_ws, size_t ws_size,
                              hipStream_t stream) {
    const float* src  = (const float*)d_in[0];
    const int*   mask = (const int*)d_in[1];
    const int*   ts   = (const int*)d_in[2];
    const float* attb = (const float*)d_in[3];
    const float* Wada = (const float*)d_in[4];
    const float* bada = (const float*)d_in[5];
    const float* Wq   = (const float*)d_in[6];
    const float* bq   = (const float*)d_in[7];
    const float* Wk   = (const float*)d_in[8];
    const float* bk   = (const float*)d_in[9];
    const float* Wv   = (const float*)d_in[10];
    const float* bv   = (const float*)d_in[11];
    const float* Wo   = (const float*)d_in[12];
    const float* bo   = (const float*)d_in[13];
    const float* W1   = (const float*)d_in[14];
    const float* b1   = (const float*)d_in[15];
    const float* W2   = (const float*)d_in[16];
    const float* b2   = (const float*)d_in[17];
    const float* g2   = (const float*)d_in[18];
    const float* bt2  = (const float*)d_in[19];
    float* out = (float*)d_out;

    const size_t MB = 1024 * 1024;
    const size_t NEED = 65536 + 36 * MB;  // proven available in round 11
    if (ws_size < NEED) {
        fill0_kernel<<<(size_t)MROWS * DM / 256, 256, 0, stream>>>(out);
        return;
    }

    char* ws = (char*)d_ws;
    float* semb = (float*)(ws + 4096);
    float* ss   = (float*)(ws + 24576);
    char*  base = ws + 65536;
    unsigned short* slotA = (unsigned short*)(base);            // xb -> mid
    unsigned short* slotB = (unsigned short*)(base + 4 * MB);   // qb -> x2
    unsigned short* slotC = (unsigned short*)(base + 8 * MB);   // kb -> h
    unsigned short* vb   = (unsigned short*)d_out;
    unsigned short* ctxb = (unsigned short*)((char*)d_out + 4 * MB);
    unsigned short* xb = slotA;
    unsigned short* qb = slotB;
    unsigned short* kb = slotC;
    unsigned short* x2 = slotB;
    unsigned short* hb = slotC;
    unsigned short* mid = slotA;
    float* adap = (float*)slotC;

    unsigned short* Wtq = (unsigned short*)(base + 12 * MB);
    unsigned short* Wtk = Wtq + 1024 * 1024;
    unsigned short* Wtv = Wtk + 1024 * 1024;
    unsigned short* Wto = Wtv + 1024 * 1024;
    unsigned short* Wt1 = Wto + 1024 * 1024;               // [4096][1024]
    unsigned short* Wt2 = Wt1 + (size_t)4096 * 1024;       // [1024][4096]

    tconv4_kernel<<<dim3(32, 16, 4), 256, 0, stream>>>(Wq, Wk, Wv, Wo, Wtq, Wtk, Wtv, Wto);
    tconv_kernel<<<dim3(128, 16), 256, 0, stream>>>(W1, Wt1, 1024, 4096);
    tconv_kernel<<<dim3(32, 64), 256, 0, stream>>>(W2, Wt2, 4096, 1024);

    semb_kernel<<<4, 256, 0, stream>>>(ts, semb);
    ada_part_kernel<<<dim3(16, 16), 256, 0, stream>>>(semb, Wada, adap);
    ada_red_kernel<<<32, 256, 0, stream>>>(adap, bada, ss);
    adaln_kernel<<<MROWS, 256, 0, stream>>>(src, ss, xb);

    gemm_bt<0><<<dim3(8, 32, 3), 256, 0, stream>>>(xb, Wtq, Wtk, Wtv, bq, bk, bv, nullptr,
                                                   qb, kb, vb, nullptr, MROWS, DM, DM, DM);
    attn_mfma<<<dim3(SEQ / QB2, NH, BATCH), 128, 0, stream>>>(qb, kb, vb, attb, mask, ctxb);
    gemm_bt<1><<<dim3(8, 32), 256, 0, stream>>>(ctxb, Wto, Wto, Wto, bo, bo, bo, xb,
                                                x2, x2, x2, nullptr, MROWS, DM, DM, DM);
    ln2_kernel<<<MROWS, 256, 0, stream>>>(x2, g2, bt2, hb);
    for (int nc = 0; nc < 4; ++nc) {
        const unsigned short* w1c = Wt1 + (size_t)nc * 1024 * 1024;
        const float* b1c = b1 + nc * 1024;
        gemm_bt<2><<<dim3(8, 32), 256, 0, stream>>>(hb, w1c, w1c, w1c, b1c, b1c, b1c,
                                                    nullptr, mid, mid, mid, nullptr,
                                                    MROWS, DM, DM, DM);
        const unsigned short* w2c = Wt2 + nc * 1024;
        if (nc == 0)
            gemm_bt<3><<<dim3(8, 32), 256, 0, stream>>>(mid, w2c, w2c, w2c, b2, b2, b2,
                                                        x2, nullptr, nullptr, nullptr, out,
                                                        MROWS, DM, DM, DFF);
        else
            gemm_bt<4><<<dim3(8, 32), 256, 0, stream>>>(mid, w2c, w2c, w2c,
                                                        nullptr, nullptr, nullptr, nullptr,
                                                        nullptr, nullptr, nullptr, out,
                                                        MROWS, DM, DM, DFF);
    }
}

// Round 14
// 190.506 us; speedup vs baseline: 1.3229x; 1.2872x over previous
//
#include <hip/hip_runtime.h>
#include <math.h>

typedef __bf16 bf16x8 __attribute__((ext_vector_type(8)));
typedef float  f32x4  __attribute__((ext_vector_type(4)));
typedef unsigned short u16x8 __attribute__((ext_vector_type(8)));

__device__ __forceinline__ float bf2f(unsigned short u) {
    return __uint_as_float(((unsigned int)u) << 16);
}
__device__ __forceinline__ unsigned short f2bf_n(float f) {
    return __builtin_bit_cast(unsigned short, (__bf16)f);  // native cvt (RNE)
}

// dims
#define BATCH 4
#define SEQ 512
#define DM 1024
#define NH 16
#define DH 64
#define DFF 4096
#define MROWS (BATCH * SEQ)   // 2048

__global__ __launch_bounds__(256) void fill0_kernel(float* __restrict__ out) {
    out[blockIdx.x * 256 + threadIdx.x] = 0.0f;
}

// ---------------- weight transpose+convert: in[K][N] f32 -> out[N][K] bf16 ----------
__global__ __launch_bounds__(256) void tconv_kernel(const float* __restrict__ in,
                                                    unsigned short* __restrict__ out,
                                                    int K, int N) {
    __shared__ float tile[64][33];
    const int n0 = blockIdx.x * 32, k0 = blockIdx.y * 64;
    const int t = threadIdx.x;
    const int tx = t & 31, ty = t >> 5;
    #pragma unroll
    for (int i = 0; i < 8; ++i)
        tile[ty + i * 8][tx] = in[(size_t)(k0 + ty + i * 8) * N + n0 + tx];
    __syncthreads();
    const int nr = t >> 3;
    const int ks = (t & 7) * 8;
    u16x8 v;
    #pragma unroll
    for (int j = 0; j < 8; ++j) v[j] = f2bf_n(tile[ks + j][nr]);
    *(u16x8*)&out[(size_t)(n0 + nr) * K + k0 + ks] = v;
}

// fused 4x (1024x1024) transpose
__global__ __launch_bounds__(256) void tconv4_kernel(const float* __restrict__ i0,
                                                     const float* __restrict__ i1,
                                                     const float* __restrict__ i2,
                                                     const float* __restrict__ i3,
                                                     unsigned short* __restrict__ o0,
                                                     unsigned short* __restrict__ o1,
                                                     unsigned short* __restrict__ o2,
                                                     unsigned short* __restrict__ o3) {
    const int z = blockIdx.z;
    const float* in = (z == 0) ? i0 : (z == 1) ? i1 : (z == 2) ? i2 : i3;
    unsigned short* out = (z == 0) ? o0 : (z == 1) ? o1 : (z == 2) ? o2 : o3;
    __shared__ float tile[64][33];
    const int n0 = blockIdx.x * 32, k0 = blockIdx.y * 64;
    const int t = threadIdx.x;
    const int tx = t & 31, ty = t >> 5;
    #pragma unroll
    for (int i = 0; i < 8; ++i)
        tile[ty + i * 8][tx] = in[(size_t)(k0 + ty + i * 8) * 1024 + n0 + tx];
    __syncthreads();
    const int nr = t >> 3;
    const int ks = (t & 7) * 8;
    u16x8 v;
    #pragma unroll
    for (int j = 0; j < 8; ++j) v[j] = f2bf_n(tile[ks + j][nr]);
    *(u16x8*)&out[(size_t)(n0 + nr) * 1024 + k0 + ks] = v;
}

// ---------------- 1) sinusoidal emb + silu ----------------
__global__ void semb_kernel(const int* __restrict__ ts, float* __restrict__ semb) {
    int b = blockIdx.x;
    float x = (float)ts[b] * 40.0f;
    for (int j = threadIdx.x; j < 1024; j += 256) {
        int idx = (j < 512) ? j : (j - 512);
        float fr = expf(-9.210340371976184f * (float)idx / 511.0f);
        float e = x * fr;
        float v = (j < 512) ? sinf(e) : cosf(e);
        semb[b * 1024 + j] = v / (1.0f + expf(-v));
    }
}

// ---------------- 2a) ada partials ----------------
__global__ __launch_bounds__(256) void ada_part_kernel(const float* __restrict__ semb,
                                                       const float* __restrict__ W,
                                                       float* __restrict__ part) {
    const int nb = blockIdx.x, kc = blockIdx.y;
    const int t = threadIdx.x;
    __shared__ float e_s[4][64];
    e_s[t >> 6][t & 63] = semb[(t >> 6) * 1024 + kc * 64 + (t & 63)];
    __syncthreads();
    const int n = nb * 128 + (t & 127);
    const int half = t >> 7;
    float a0 = 0.f, a1 = 0.f, a2 = 0.f, a3 = 0.f;
    const int kk0 = half * 32;
    #pragma unroll 8
    for (int kk = kk0; kk < kk0 + 32; ++kk) {
        const float w = W[(size_t)(kc * 64 + kk) * 2048 + n];
        a0 += e_s[0][kk] * w; a1 += e_s[1][kk] * w;
        a2 += e_s[2][kk] * w; a3 += e_s[3][kk] * w;
    }
    const int j = kc * 2 + half;
    float* p = part + (size_t)j * 4 * 2048 + n;
    p[0] = a0; p[2048] = a1; p[2 * 2048] = a2; p[3 * 2048] = a3;
}

// ---------------- 2b) ada reduce ----------------
__global__ __launch_bounds__(256) void ada_red_kernel(const float* __restrict__ part,
                                                      const float* __restrict__ bias,
                                                      float* __restrict__ ss) {
    const int idx = blockIdx.x * 256 + threadIdx.x;
    const int b = idx >> 11, n = idx & 2047;
    float acc = bias[n];
    #pragma unroll 8
    for (int j = 0; j < 32; ++j) acc += part[((size_t)j * 4 + b) * 2048 + n];
    ss[b * 2048 + n] = acc;
}

// ---------------- 3) AdaLN ----------------
__global__ __launch_bounds__(256) void adaln_kernel(const float* __restrict__ src,
                                                    const float* __restrict__ ss,
                                                    unsigned short* __restrict__ xb) {
    int r = blockIdx.x;
    int b = r >> 9;
    int t = threadIdx.x;
    float4 v4 = *reinterpret_cast<const float4*>(&src[(size_t)r * DM + t * 4]);
    float v[4] = {v4.x, v4.y, v4.z, v4.w};
    float s = v[0] + v[1] + v[2] + v[3];
    float q = v[0]*v[0] + v[1]*v[1] + v[2]*v[2] + v[3]*v[3];
    #pragma unroll
    for (int off = 32; off > 0; off >>= 1) { s += __shfl_down(s, off); q += __shfl_down(q, off); }
    __shared__ float red[8];
    if ((t & 63) == 0) { red[t >> 6] = s; red[4 + (t >> 6)] = q; }
    __syncthreads();
    s = red[0] + red[1] + red[2] + red[3];
    q = red[4] + red[5] + red[6] + red[7];
    float mean = s * (1.0f / DM);
    float var = q * (1.0f / DM) - mean * mean;
    float rstd = rsqrtf(var + 1e-5f);
    ushort4 o;
    o.x = f2bf_n((v[0]-mean)*rstd*(1.0f+ss[b*2048 + t*4+0]) + ss[b*2048+1024 + t*4+0]);
    o.y = f2bf_n((v[1]-mean)*rstd*(1.0f+ss[b*2048 + t*4+1]) + ss[b*2048+1024 + t*4+1]);
    o.z = f2bf_n((v[2]-mean)*rstd*(1.0f+ss[b*2048 + t*4+2]) + ss[b*2048+1024 + t*4+2]);
    o.w = f2bf_n((v[3]-mean)*rstd*(1.0f+ss[b*2048 + t*4+3]) + ss[b*2048+1024 + t*4+3]);
    *reinterpret_cast<ushort4*>(&xb[(size_t)r * DM + t * 4]) = o;
}

// ---------------- LN2 ----------------
__global__ __launch_bounds__(256) void ln2_kernel(const unsigned short* __restrict__ x,
                                                  const float* __restrict__ g2,
                                                  const float* __restrict__ beta2,
                                                  unsigned short* __restrict__ hout) {
    int r = blockIdx.x;
    int t = threadIdx.x;
    ushort4 s4 = *reinterpret_cast<const ushort4*>(&x[(size_t)r * DM + t * 4]);
    float v[4] = {bf2f(s4.x), bf2f(s4.y), bf2f(s4.z), bf2f(s4.w)};
    float s = v[0] + v[1] + v[2] + v[3];
    float q = v[0]*v[0] + v[1]*v[1] + v[2]*v[2] + v[3]*v[3];
    #pragma unroll
    for (int off = 32; off > 0; off >>= 1) { s += __shfl_down(s, off); q += __shfl_down(q, off); }
    __shared__ float red[8];
    if ((t & 63) == 0) { red[t >> 6] = s; red[4 + (t >> 6)] = q; }
    __syncthreads();
    s = red[0] + red[1] + red[2] + red[3];
    q = red[4] + red[5] + red[6] + red[7];
    float mean = s * (1.0f / DM);
    float var = q * (1.0f / DM) - mean * mean;
    float rstd = rsqrtf(var + 1e-5f);
    ushort4 o;
    o.x = f2bf_n((v[0]-mean)*rstd*g2[t*4+0] + beta2[t*4+0]);
    o.y = f2bf_n((v[1]-mean)*rstd*g2[t*4+1] + beta2[t*4+1]);
    o.z = f2bf_n((v[2]-mean)*rstd*g2[t*4+2] + beta2[t*4+2]);
    o.w = f2bf_n((v[3]-mean)*rstd*g2[t*4+3] + beta2[t*4+3]);
    *reinterpret_cast<ushort4*>(&hout[(size_t)r * DM + t * 4]) = o;
}

// ============ bf16-weight GEMM (verified) ============
#define TBM 64
#define TBN 128
#define TBK 64
#define PIT 72

template<int MODE>
__global__ __launch_bounds__(256) void gemm_bt(
    const unsigned short* __restrict__ A,
    const unsigned short* __restrict__ Wta, const unsigned short* __restrict__ Wtb,
    const unsigned short* __restrict__ Wtc,
    const float* __restrict__ ba, const float* __restrict__ bbb, const float* __restrict__ bc,
    const unsigned short* __restrict__ resid,
    unsigned short* __restrict__ oa, unsigned short* __restrict__ ob,
    unsigned short* __restrict__ oc,
    float* __restrict__ outF,
    int M, int N, int K, int ldk)
{
    const int gx = gridDim.x, gy = gridDim.y;
    const int nwg = gx * gy * gridDim.z;
    const int wid = blockIdx.x + gx * (blockIdx.y + gy * blockIdx.z);
    const int aid = (wid & 7) * (nwg >> 3) + (wid >> 3);
    const int bx = aid % gx;
    const int by = (aid / gx) % gy;
    const int sel = aid / (gx * gy);

    const unsigned short* Wt = (sel == 0) ? Wta : (sel == 1) ? Wtb : Wtc;
    const float* bias = (sel == 0) ? ba : (sel == 1) ? bbb : bc;
    unsigned short* outB = (sel == 0) ? oa : (sel == 1) ? ob : oc;

    __shared__ unsigned short As[2][TBM * PIT];
    __shared__ unsigned short Bs[2][TBN * PIT];
    const int t = threadIdx.x;
    const int lane = t & 63;
    const int w = t >> 6, wm = w >> 1, wn = w & 1;
    const int l15 = lane & 15, l4 = lane >> 4;
    const int m0 = by * TBM, n0 = bx * TBN;

    f32x4 acc[2][4];
    #pragma unroll
    for (int i = 0; i < 2; ++i)
        #pragma unroll
        for (int j = 0; j < 4; ++j)
            #pragma unroll
            for (int r = 0; r < 4; ++r) acc[i][j][r] = 0.0f;

    const int ar = t >> 2, aseg = (t & 3) * 16;
    const unsigned short* aG = A + (size_t)(m0 + ar) * K + aseg;
    const int aLo = ar * PIT + aseg;
    const int br = t >> 1, bseg = (t & 1) * 32;
    const unsigned short* bG = Wt + (size_t)(n0 + br) * ldk + bseg;
    const int bLo = br * PIT + bseg;

    u16x8 ra0 = *(const u16x8*)(aG);
    u16x8 ra1 = *(const u16x8*)(aG + 8);
    u16x8 rb0 = *(const u16x8*)(bG);
    u16x8 rb1 = *(const u16x8*)(bG + 8);
    u16x8 rb2 = *(const u16x8*)(bG + 16);
    u16x8 rb3 = *(const u16x8*)(bG + 24);
    *(u16x8*)&As[0][aLo] = ra0; *(u16x8*)&As[0][aLo + 8] = ra1;
    *(u16x8*)&Bs[0][bLo] = rb0; *(u16x8*)&Bs[0][bLo + 8] = rb1;
    *(u16x8*)&Bs[0][bLo + 16] = rb2; *(u16x8*)&Bs[0][bLo + 24] = rb3;
    __syncthreads();

    const int NT = K / TBK;
    for (int kt = 0; kt < NT; ++kt) {
        const int cur = kt & 1;
        const bool more = (kt + 1 < NT);
        if (more) {
            const int k0 = (kt + 1) * TBK;
            ra0 = *(const u16x8*)(aG + k0);
            ra1 = *(const u16x8*)(aG + k0 + 8);
            rb0 = *(const u16x8*)(bG + k0);
            rb1 = *(const u16x8*)(bG + k0 + 8);
            rb2 = *(const u16x8*)(bG + k0 + 16);
            rb3 = *(const u16x8*)(bG + k0 + 24);
        }
        #pragma unroll
        for (int kk = 0; kk < 2; ++kk) {
            bf16x8 af[2], bfr[4];
            #pragma unroll
            for (int mt = 0; mt < 2; ++mt) {
                u16x8 tmp = *(const u16x8*)&As[cur][(wm*32 + mt*16 + l15) * PIT + kk*32 + l4*8];
                af[mt] = __builtin_bit_cast(bf16x8, tmp);
            }
            #pragma unroll
            for (int nt = 0; nt < 4; ++nt) {
                u16x8 tmp = *(const u16x8*)&Bs[cur][(wn*64 + nt*16 + l15) * PIT + kk*32 + l4*8];
                bfr[nt] = __builtin_bit_cast(bf16x8, tmp);
            }
            #pragma unroll
            for (int mt = 0; mt < 2; ++mt)
                #pragma unroll
                for (int nt = 0; nt < 4; ++nt)
                    acc[mt][nt] = __builtin_amdgcn_mfma_f32_16x16x32_bf16(
                        af[mt], bfr[nt], acc[mt][nt], 0, 0, 0);
        }
        if (more) {
            const int nx = cur ^ 1;
            *(u16x8*)&As[nx][aLo] = ra0; *(u16x8*)&As[nx][aLo + 8] = ra1;
            *(u16x8*)&Bs[nx][bLo] = rb0; *(u16x8*)&Bs[nx][bLo + 8] = rb1;
            *(u16x8*)&Bs[nx][bLo + 16] = rb2; *(u16x8*)&Bs[nx][bLo + 24] = rb3;
            __syncthreads();
        }
    }

    #pragma unroll
    for (int mt = 0; mt < 2; ++mt) {
        const int mbase = m0 + wm*32 + mt*16 + l4*4;
        #pragma unroll
        for (int nt = 0; nt < 4; ++nt) {
            const int n = n0 + wn*64 + nt*16 + l15;
            const float bs = (MODE == 4) ? 0.0f : bias[n];
            #pragma unroll
            for (int r = 0; r < 4; ++r) {
                const int m = mbase + r;
                float v = acc[mt][nt][r] + bs;
                if (MODE == 2) v = v / (1.0f + expf(-1.702f * v));
                if (MODE == 1 || MODE == 3) v += bf2f(resid[(size_t)m * N + n]);
                if (MODE == 3)      outF[(size_t)m * N + n] = v;
                else if (MODE == 4) outF[(size_t)m * N + n] += v;
                else                outB[(size_t)m * N + n] = f2bf_n(v);
            }
        }
    }
}

// ---------- MFMA flash attention: bf16 Sb (27.6 KB LDS -> 5 blocks/CU) ----------
#define QB2 32
#define AKT 64
#define KROW 72
#define VROW 72
#define PROW 72
#define SBPIT 72   // u16 pitch for combined bias/mask tile (144B rows, 2-way free)

__global__ __launch_bounds__(128) void attn_mfma(const unsigned short* __restrict__ qbuf,
                                                 const unsigned short* __restrict__ kbuf,
                                                 const unsigned short* __restrict__ vbuf,
                                                 const float* __restrict__ attb,
                                                 const int* __restrict__ mask,
                                                 unsigned short* __restrict__ ctx) {
    __shared__ unsigned short Ks[AKT * KROW];      // 9216 B
    __shared__ unsigned short Vt[DH * VROW];       // 9216 B
    __shared__ unsigned short Pb[2 * 16 * PROW];   // 4608 B
    __shared__ unsigned short Sb[QB2 * SBPIT];     // 4608 B  (bf16 combined bias/mask)
    const int t = threadIdx.x;       // 0..127
    const int lane = t & 63;
    const int w = t >> 6;
    const int l15 = lane & 15, l4 = lane >> 4;
    const int q0 = blockIdx.x * QB2;
    const int h = blockIdx.y;
    const int b = blockIdx.z;

    bf16x8 qf[2];
    {
        const unsigned short* qrow = qbuf + ((size_t)(b * SEQ + q0 + w * 16 + l15)) * DM + h * DH;
        u16x8 t0 = *(const u16x8*)(qrow + l4 * 8);
        u16x8 t1 = *(const u16x8*)(qrow + 32 + l4 * 8);
        qf[0] = __builtin_bit_cast(bf16x8, t0);
        qf[1] = __builtin_bit_cast(bf16x8, t1);
    }

    float m[4] = {-1e30f, -1e30f, -1e30f, -1e30f};
    float l[4] = {0.0f, 0.0f, 0.0f, 0.0f};
    f32x4 o[4];
    #pragma unroll
    for (int dt = 0; dt < 4; ++dt)
        #pragma unroll
        for (int r = 0; r < 4; ++r) o[dt][r] = 0.0f;

    unsigned short* Pw = Pb + w * 16 * PROW;

    const int kr = t >> 1, c0 = (t & 1) * 32;      // K staging map
    const int kp = t & 31, vg = t >> 5;            // V staging map

    u16x8 rk0, rk1, rk2, rk3, rv0, rv1, rv2, rv3;
    float4 rb[4];
    int4   rm[4];

#define LOADT(KT) {                                                                     \
    const int kbase = (KT) * AKT;                                                       \
    const unsigned short* gk = kbuf + ((size_t)(b * SEQ + kbase + kr)) * DM + h * DH + c0; \
    rk0 = *(const u16x8*)gk;        rk1 = *(const u16x8*)(gk + 8);                      \
    rk2 = *(const u16x8*)(gk + 16); rk3 = *(const u16x8*)(gk + 24);                     \
    const unsigned short* gv = vbuf + ((size_t)(b * SEQ + kbase + 2 * kp)) * DM + h * DH + vg * 8; \
    rv0 = *(const u16x8*)gv;        rv1 = *(const u16x8*)(gv + DM);                     \
    rv2 = *(const u16x8*)(gv + 32); rv3 = *(const u16x8*)(gv + DM + 32);                \
    const float* bp = attb + (((size_t)(b * NH + h)) * SEQ + (q0 + w * 16)) * SEQ + kbase; \
    const int* mp = mask + ((size_t)(b * SEQ) + q0 + w * 16) * SEQ + kbase;             \
    _Pragma("unroll")                                                                   \
    for (int i = 0; i < 4; ++i) {                                                       \
        const int e = lane + i * 64; const int row = e >> 4, cg = e & 15;               \
        rb[i] = *(const float4*)&bp[(size_t)row * SEQ + cg * 4];                        \
        rm[i] = *(const int4*)&mp[(size_t)row * SEQ + cg * 4];                          \
    } }

#define STORET() {                                                                      \
    unsigned short* s = Ks + kr * KROW + c0;                                            \
    *(u16x8*)s = rk0; *(u16x8*)(s + 8) = rk1;                                           \
    *(u16x8*)(s + 16) = rk2; *(u16x8*)(s + 24) = rk3;                                   \
    unsigned int* vt32 = (unsigned int*)Vt;                                             \
    _Pragma("unroll")                                                                   \
    for (int j = 0; j < 8; ++j) {                                                       \
        vt32[(vg * 8 + j) * (VROW / 2) + kp] =                                          \
            (unsigned int)rv0[j] | ((unsigned int)rv1[j] << 16);                        \
        vt32[((vg + 4) * 8 + j) * (VROW / 2) + kp] =                                    \
            (unsigned int)rv2[j] | ((unsigned int)rv3[j] << 16);                        \
    }                                                                                   \
    _Pragma("unroll")                                                                   \
    for (int i = 0; i < 4; ++i) {                                                       \
        const int e = lane + i * 64; const int row = e >> 4, cg = e & 15;               \
        ushort4 cc;                                                                     \
        cc.x = f2bf_n(rm[i].x ? -8e30f : 8.0f * rb[i].x);                               \
        cc.y = f2bf_n(rm[i].y ? -8e30f : 8.0f * rb[i].y);                               \
        cc.z = f2bf_n(rm[i].z ? -8e30f : 8.0f * rb[i].z);                               \
        cc.w = f2bf_n(rm[i].w ? -8e30f : 8.0f * rb[i].w);                               \
        *(ushort4*)&Sb[(w * 16 + row) * SBPIT + cg * 4] = cc;                           \
    } }

    LOADT(0);
    for (int kt = 0; kt < SEQ / AKT; ++kt) {
        __syncthreads();
        STORET();
        __syncthreads();
        if (kt + 1 < SEQ / AKT) LOADT(kt + 1);

        f32x4 acc[4];
        #pragma unroll
        for (int nt = 0; nt < 4; ++nt)
            #pragma unroll
            for (int r = 0; r < 4; ++r)
                acc[nt][r] = bf2f(Sb[(w * 16 + l4 * 4 + r) * SBPIT + nt * 16 + l15]);

        #pragma unroll
        for (int kk = 0; kk < 2; ++kk) {
            #pragma unroll
            for (int nt = 0; nt < 4; ++nt) {
                u16x8 tmp = *(const u16x8*)(Ks + (nt * 16 + l15) * KROW + kk * 32 + l4 * 8);
                acc[nt] = __builtin_amdgcn_mfma_f32_16x16x32_bf16(
                    qf[kk], __builtin_bit_cast(bf16x8, tmp), acc[nt], 0, 0, 0);
            }
        }

        float pm[4] = {-1e30f, -1e30f, -1e30f, -1e30f};
        #pragma unroll
        for (int nt = 0; nt < 4; ++nt) {
            #pragma unroll
            for (int r = 0; r < 4; ++r) {
                const float sv = acc[nt][r] * 0.125f;
                acc[nt][r] = sv;
                pm[r] = fmaxf(pm[r], sv);
            }
        }
        #pragma unroll
        for (int r = 0; r < 4; ++r) {
            #pragma unroll
            for (int off = 1; off < 16; off <<= 1)
                pm[r] = fmaxf(pm[r], __shfl_xor(pm[r], off));
        }
        float al[4], ps[4];
        #pragma unroll
        for (int r = 0; r < 4; ++r) {
            const float mn = fmaxf(m[r], pm[r]);
            al[r] = __expf(m[r] - mn);
            m[r] = mn;
            ps[r] = 0.0f;
        }
        #pragma unroll
        for (int nt = 0; nt < 4; ++nt) {
            #pragma unroll
            for (int r = 0; r < 4; ++r) {
                const float p = __expf(acc[nt][r] - m[r]);
                acc[nt][r] = p;
                ps[r] += p;
            }
        }
        #pragma unroll
        for (int r = 0; r < 4; ++r) {
            #pragma unroll
            for (int off = 1; off < 16; off <<= 1) ps[r] += __shfl_xor(ps[r], off);
            l[r] = l[r] * al[r] + ps[r];
        }
        #pragma unroll
        for (int dt = 0; dt < 4; ++dt)
            #pragma unroll
            for (int r = 0; r < 4; ++r) o[dt][r] *= al[r];

        #pragma unroll
        for (int nt = 0; nt < 4; ++nt)
            #pragma unroll
            for (int r = 0; r < 4; ++r)
                Pw[(l4 * 4 + r) * PROW + nt * 16 + l15] = f2bf_n(acc[nt][r]);

        #pragma unroll
        for (int ks = 0; ks < 2; ++ks) {
            u16x8 pa = *(const u16x8*)(Pw + l15 * PROW + ks * 32 + l4 * 8);
            #pragma unroll
            for (int dt = 0; dt < 4; ++dt) {
                u16x8 vv = *(const u16x8*)(Vt + (dt * 16 + l15) * VROW + ks * 32 + l4 * 8);
                o[dt] = __builtin_amdgcn_mfma_f32_16x16x32_bf16(
                    __builtin_bit_cast(bf16x8, pa), __builtin_bit_cast(bf16x8, vv),
                    o[dt], 0, 0, 0);
            }
        }
    }

    #pragma unroll
    for (int r = 0; r < 4; ++r) {
        const float inv = 1.0f / l[r];
        const size_t row = (size_t)(b * SEQ + q0 + w * 16 + l4 * 4 + r) * DM + h * DH;
        #pragma unroll
        for (int dt = 0; dt < 4; ++dt)
            ctx[row + dt * 16 + l15] = f2bf_n(o[dt][r] * inv);
    }
#undef LOADT
#undef STORET
}

// ---------------- host launch ----------------
extern "C" void kernel_launch(void* const* d_in, const int* in_sizes, int n_in,
                              void* d_out, int out_size, void* d_ws, size_t ws_size,
                              hipStream_t stream) {
    const float* src  = (const float*)d_in[0];
    const int*   mask = (const int*)d_in[1];
    const int*   ts   = (const int*)d_in[2];
    const float* attb = (const float*)d_in[3];
    const float* Wada = (const float*)d_in[4];
    const float* bada = (const float*)d_in[5];
    const float* Wq   = (const float*)d_in[6];
    const float* bq   = (const float*)d_in[7];
    const float* Wk   = (const float*)d_in[8];
    const float* bk   = (const float*)d_in[9];
    const float* Wv   = (const float*)d_in[10];
    const float* bv   = (const float*)d_in[11];
    const float* Wo   = (const float*)d_in[12];
    const float* bo   = (const float*)d_in[13];
    const float* W1   = (const float*)d_in[14];
    const float* b1   = (const float*)d_in[15];
    const float* W2   = (const float*)d_in[16];
    const float* b2   = (const float*)d_in[17];
    const float* g2   = (const float*)d_in[18];
    const float* bt2  = (const float*)d_in[19];
    float* out = (float*)d_out;

    const size_t MB = 1024 * 1024;
    const size_t NEED = 65536 + 36 * MB;       // proven available (round 11)
    const size_t NEED_FULL = 65536 + 52 * MB;  // full-mid FFN path
    if (ws_size < NEED) {
        fill0_kernel<<<(size_t)MROWS * DM / 256, 256, 0, stream>>>(out);
        return;
    }
    const bool FULL = (ws_size >= NEED_FULL);

    char* ws = (char*)d_ws;
    float* semb = (float*)(ws + 4096);
    float* ss   = (float*)(ws + 24576);
    char*  base = ws + 65536;
    unsigned short* slotA = (unsigned short*)(base);            // xb -> mid(chunked)
    unsigned short* slotB = (unsigned short*)(base + 4 * MB);   // qb -> x2
    unsigned short* slotC = (unsigned short*)(base + 8 * MB);   // kb -> h
    unsigned short* vb   = (unsigned short*)d_out;
    unsigned short* ctxb = (unsigned short*)((char*)d_out + 4 * MB);
    unsigned short* xb = slotA;
    unsigned short* qb = slotB;
    unsigned short* kb = slotC;
    unsigned short* x2 = slotB;
    unsigned short* hb = slotC;
    unsigned short* midc = slotA;
    float* adap = (float*)slotC;

    unsigned short* Wtq = (unsigned short*)(base + 12 * MB);
    unsigned short* Wtk = Wtq + 1024 * 1024;
    unsigned short* Wtv = Wtk + 1024 * 1024;
    unsigned short* Wto = Wtv + 1024 * 1024;
    unsigned short* Wt1 = Wto + 1024 * 1024;               // [4096][1024]
    unsigned short* Wt2 = Wt1 + (size_t)4096 * 1024;       // [1024][4096]
    unsigned short* midF = (unsigned short*)(base + 36 * MB);  // [2048][4096] (FULL path)

    tconv4_kernel<<<dim3(32, 16, 4), 256, 0, stream>>>(Wq, Wk, Wv, Wo, Wtq, Wtk, Wtv, Wto);
    tconv_kernel<<<dim3(128, 16), 256, 0, stream>>>(W1, Wt1, 1024, 4096);
    tconv_kernel<<<dim3(32, 64), 256, 0, stream>>>(W2, Wt2, 4096, 1024);

    semb_kernel<<<4, 256, 0, stream>>>(ts, semb);
    ada_part_kernel<<<dim3(16, 16), 256, 0, stream>>>(semb, Wada, adap);
    ada_red_kernel<<<32, 256, 0, stream>>>(adap, bada, ss);
    adaln_kernel<<<MROWS, 256, 0, stream>>>(src, ss, xb);

    gemm_bt<0><<<dim3(8, 32, 3), 256, 0, stream>>>(xb, Wtq, Wtk, Wtv, bq, bk, bv, nullptr,
                                                   qb, kb, vb, nullptr, MROWS, DM, DM, DM);
    attn_mfma<<<dim3(SEQ / QB2, NH, BATCH), 128, 0, stream>>>(qb, kb, vb, attb, mask, ctxb);
    gemm_bt<1><<<dim3(8, 32), 256, 0, stream>>>(ctxb, Wto, Wto, Wto, bo, bo, bo, xb,
                                                x2, x2, x2, nullptr, MROWS, DM, DM, DM);
    ln2_kernel<<<MROWS, 256, 0, stream>>>(x2, g2, bt2, hb);

    if (FULL) {
        // FFN as 2 dispatches: mid = gelu2(h@W1+b1) [2048x4096]; out = mid@W2+b2+x2
        gemm_bt<2><<<dim3(32, 32), 256, 0, stream>>>(hb, Wt1, Wt1, Wt1, b1, b1, b1, nullptr,
                                                     midF, midF, midF, nullptr,
                                                     MROWS, DFF, DM, DM);
        gemm_bt<3><<<dim3(8, 32), 256, 0, stream>>>(midF, Wt2, Wt2, Wt2, b2, b2, b2, x2,
                                                    nullptr, nullptr, nullptr, out,
                                                    MROWS, DM, DFF, DFF);
    } else {
        for (int nc = 0; nc < 4; ++nc) {
            const unsigned short* w1c = Wt1 + (size_t)nc * 1024 * 1024;
            const float* b1c = b1 + nc * 1024;
            gemm_bt<2><<<dim3(8, 32), 256, 0, stream>>>(hb, w1c, w1c, w1c, b1c, b1c, b1c,
                                                        nullptr, midc, midc, midc, nullptr,
                                                        MROWS, DM, DM, DM);
            const unsigned short* w2c = Wt2 + nc * 1024;
            if (nc == 0)
                gemm_bt<3><<<dim3(8, 32), 256, 0, stream>>>(midc, w2c, w2c, w2c, b2, b2, b2,
                                                            x2, nullptr, nullptr, nullptr, out,
                                                            MROWS, DM, DM, DFF);
            else
                gemm_bt<4><<<dim3(8, 32), 256, 0, stream>>>(midc, w2c, w2c, w2c,
                                                            nullptr, nullptr, nullptr, nullptr,
                                                            nullptr, nullptr, nullptr, out,
                                                            MROWS, DM, DM, DFF);
        }
    }
}

// Round 15
// 187.067 us; speedup vs baseline: 1.3473x; 1.0184x over previous
//
#include <hip/hip_runtime.h>
#include <math.h>

typedef __bf16 bf16x8 __attribute__((ext_vector_type(8)));
typedef float  f32x4  __attribute__((ext_vector_type(4)));
typedef unsigned short u16x8 __attribute__((ext_vector_type(8)));

__device__ __forceinline__ float bf2f(unsigned short u) {
    return __uint_as_float(((unsigned int)u) << 16);
}
__device__ __forceinline__ unsigned short f2bf_n(float f) {
    return __builtin_bit_cast(unsigned short, (__bf16)f);  // native cvt (RNE)
}

// dims
#define BATCH 4
#define SEQ 512
#define DM 1024
#define NH 16
#define DH 64
#define DFF 4096
#define MROWS (BATCH * SEQ)   // 2048

__global__ __launch_bounds__(256) void fill0_kernel(float* __restrict__ out) {
    out[blockIdx.x * 256 + threadIdx.x] = 0.0f;
}

// ---------------- weight transpose+convert: in[K][N] f32 -> out[N][K] bf16 ----------
__global__ __launch_bounds__(256) void tconv_kernel(const float* __restrict__ in,
                                                    unsigned short* __restrict__ out,
                                                    int K, int N) {
    __shared__ float tile[64][33];
    const int n0 = blockIdx.x * 32, k0 = blockIdx.y * 64;
    const int t = threadIdx.x;
    const int tx = t & 31, ty = t >> 5;
    #pragma unroll
    for (int i = 0; i < 8; ++i)
        tile[ty + i * 8][tx] = in[(size_t)(k0 + ty + i * 8) * N + n0 + tx];
    __syncthreads();
    const int nr = t >> 3;
    const int ks = (t & 7) * 8;
    u16x8 v;
    #pragma unroll
    for (int j = 0; j < 8; ++j) v[j] = f2bf_n(tile[ks + j][nr]);
    *(u16x8*)&out[(size_t)(n0 + nr) * K + k0 + ks] = v;
}

// fused 4x (1024x1024) transpose
__global__ __launch_bounds__(256) void tconv4_kernel(const float* __restrict__ i0,
                                                     const float* __restrict__ i1,
                                                     const float* __restrict__ i2,
                                                     const float* __restrict__ i3,
                                                     unsigned short* __restrict__ o0,
                                                     unsigned short* __restrict__ o1,
                                                     unsigned short* __restrict__ o2,
                                                     unsigned short* __restrict__ o3) {
    const int z = blockIdx.z;
    const float* in = (z == 0) ? i0 : (z == 1) ? i1 : (z == 2) ? i2 : i3;
    unsigned short* out = (z == 0) ? o0 : (z == 1) ? o1 : (z == 2) ? o2 : o3;
    __shared__ float tile[64][33];
    const int n0 = blockIdx.x * 32, k0 = blockIdx.y * 64;
    const int t = threadIdx.x;
    const int tx = t & 31, ty = t >> 5;
    #pragma unroll
    for (int i = 0; i < 8; ++i)
        tile[ty + i * 8][tx] = in[(size_t)(k0 + ty + i * 8) * 1024 + n0 + tx];
    __syncthreads();
    const int nr = t >> 3;
    const int ks = (t & 7) * 8;
    u16x8 v;
    #pragma unroll
    for (int j = 0; j < 8; ++j) v[j] = f2bf_n(tile[ks + j][nr]);
    *(u16x8*)&out[(size_t)(n0 + nr) * 1024 + k0 + ks] = v;
}

// ---------------- 1) sinusoidal emb + silu ----------------
__global__ void semb_kernel(const int* __restrict__ ts, float* __restrict__ semb) {
    int b = blockIdx.x;
    float x = (float)ts[b] * 40.0f;
    for (int j = threadIdx.x; j < 1024; j += 256) {
        int idx = (j < 512) ? j : (j - 512);
        float fr = expf(-9.210340371976184f * (float)idx / 511.0f);
        float e = x * fr;
        float v = (j < 512) ? sinf(e) : cosf(e);
        semb[b * 1024 + j] = v / (1.0f + expf(-v));
    }
}

// ---------------- 2a) ada partials ----------------
__global__ __launch_bounds__(256) void ada_part_kernel(const float* __restrict__ semb,
                                                       const float* __restrict__ W,
                                                       float* __restrict__ part) {
    const int nb = blockIdx.x, kc = blockIdx.y;
    const int t = threadIdx.x;
    __shared__ float e_s[4][64];
    e_s[t >> 6][t & 63] = semb[(t >> 6) * 1024 + kc * 64 + (t & 63)];
    __syncthreads();
    const int n = nb * 128 + (t & 127);
    const int half = t >> 7;
    float a0 = 0.f, a1 = 0.f, a2 = 0.f, a3 = 0.f;
    const int kk0 = half * 32;
    #pragma unroll 8
    for (int kk = kk0; kk < kk0 + 32; ++kk) {
        const float w = W[(size_t)(kc * 64 + kk) * 2048 + n];
        a0 += e_s[0][kk] * w; a1 += e_s[1][kk] * w;
        a2 += e_s[2][kk] * w; a3 += e_s[3][kk] * w;
    }
    const int j = kc * 2 + half;
    float* p = part + (size_t)j * 4 * 2048 + n;
    p[0] = a0; p[2048] = a1; p[2 * 2048] = a2; p[3 * 2048] = a3;
}

// ---------------- 2b) ada reduce ----------------
__global__ __launch_bounds__(256) void ada_red_kernel(const float* __restrict__ part,
                                                      const float* __restrict__ bias,
                                                      float* __restrict__ ss) {
    const int idx = blockIdx.x * 256 + threadIdx.x;
    const int b = idx >> 11, n = idx & 2047;
    float acc = bias[n];
    #pragma unroll 8
    for (int j = 0; j < 32; ++j) acc += part[((size_t)j * 4 + b) * 2048 + n];
    ss[b * 2048 + n] = acc;
}

// ---------------- 3) AdaLN ----------------
__global__ __launch_bounds__(256) void adaln_kernel(const float* __restrict__ src,
                                                    const float* __restrict__ ss,
                                                    unsigned short* __restrict__ xb) {
    int r = blockIdx.x;
    int b = r >> 9;
    int t = threadIdx.x;
    float4 v4 = *reinterpret_cast<const float4*>(&src[(size_t)r * DM + t * 4]);
    float v[4] = {v4.x, v4.y, v4.z, v4.w};
    float s = v[0] + v[1] + v[2] + v[3];
    float q = v[0]*v[0] + v[1]*v[1] + v[2]*v[2] + v[3]*v[3];
    #pragma unroll
    for (int off = 32; off > 0; off >>= 1) { s += __shfl_down(s, off); q += __shfl_down(q, off); }
    __shared__ float red[8];
    if ((t & 63) == 0) { red[t >> 6] = s; red[4 + (t >> 6)] = q; }
    __syncthreads();
    s = red[0] + red[1] + red[2] + red[3];
    q = red[4] + red[5] + red[6] + red[7];
    float mean = s * (1.0f / DM);
    float var = q * (1.0f / DM) - mean * mean;
    float rstd = rsqrtf(var + 1e-5f);
    ushort4 o;
    o.x = f2bf_n((v[0]-mean)*rstd*(1.0f+ss[b*2048 + t*4+0]) + ss[b*2048+1024 + t*4+0]);
    o.y = f2bf_n((v[1]-mean)*rstd*(1.0f+ss[b*2048 + t*4+1]) + ss[b*2048+1024 + t*4+1]);
    o.z = f2bf_n((v[2]-mean)*rstd*(1.0f+ss[b*2048 + t*4+2]) + ss[b*2048+1024 + t*4+2]);
    o.w = f2bf_n((v[3]-mean)*rstd*(1.0f+ss[b*2048 + t*4+3]) + ss[b*2048+1024 + t*4+3]);
    *reinterpret_cast<ushort4*>(&xb[(size_t)r * DM + t * 4]) = o;
}

// ---------------- LN2 ----------------
__global__ __launch_bounds__(256) void ln2_kernel(const unsigned short* __restrict__ x,
                                                  const float* __restrict__ g2,
                                                  const float* __restrict__ beta2,
                                                  unsigned short* __restrict__ hout) {
    int r = blockIdx.x;
    int t = threadIdx.x;
    ushort4 s4 = *reinterpret_cast<const ushort4*>(&x[(size_t)r * DM + t * 4]);
    float v[4] = {bf2f(s4.x), bf2f(s4.y), bf2f(s4.z), bf2f(s4.w)};
    float s = v[0] + v[1] + v[2] + v[3];
    float q = v[0]*v[0] + v[1]*v[1] + v[2]*v[2] + v[3]*v[3];
    #pragma unroll
    for (int off = 32; off > 0; off >>= 1) { s += __shfl_down(s, off); q += __shfl_down(q, off); }
    __shared__ float red[8];
    if ((t & 63) == 0) { red[t >> 6] = s; red[4 + (t >> 6)] = q; }
    __syncthreads();
    s = red[0] + red[1] + red[2] + red[3];
    q = red[4] + red[5] + red[6] + red[7];
    float mean = s * (1.0f / DM);
    float var = q * (1.0f / DM) - mean * mean;
    float rstd = rsqrtf(var + 1e-5f);
    ushort4 o;
    o.x = f2bf_n((v[0]-mean)*rstd*g2[t*4+0] + beta2[t*4+0]);
    o.y = f2bf_n((v[1]-mean)*rstd*g2[t*4+1] + beta2[t*4+1]);
    o.z = f2bf_n((v[2]-mean)*rstd*g2[t*4+2] + beta2[t*4+2]);
    o.w = f2bf_n((v[3]-mean)*rstd*g2[t*4+3] + beta2[t*4+3]);
    *reinterpret_cast<ushort4*>(&hout[(size_t)r * DM + t * 4]) = o;
}

// ============ bf16-weight GEMM: by-fastest XCD swizzle, PIT=68 (3 blocks/CU) ============
#define TBM 64
#define TBN 128
#define TBK 64
#define PIT 68   // 136B rows: frag-read bank stride 2/row -> 2-way aliasing (free)

template<int MODE>
__global__ __launch_bounds__(256) void gemm_bt(
    const unsigned short* __restrict__ A,
    const unsigned short* __restrict__ Wta, const unsigned short* __restrict__ Wtb,
    const unsigned short* __restrict__ Wtc,
    const float* __restrict__ ba, const float* __restrict__ bbb, const float* __restrict__ bc,
    const unsigned short* __restrict__ resid,
    unsigned short* __restrict__ oa, unsigned short* __restrict__ ob,
    unsigned short* __restrict__ oc,
    float* __restrict__ outF,
    int M, int N, int K, int ldk)
{
    // bijective XCD-chunked swizzle; within a chunk, by (M-block) varies FASTEST
    // so each XCD keeps a small B-slice L2-resident while streaming A.
    const int gx = gridDim.x, gy = gridDim.y;
    const int nwg = gx * gy * gridDim.z;
    const int wid = blockIdx.x + gx * (blockIdx.y + gy * blockIdx.z);
    const int aid = (wid & 7) * (nwg >> 3) + (wid >> 3);
    const int plane = gx * gy;
    const int sel = aid / plane;
    const int pid = aid % plane;
    const int by = pid % gy;
    const int bx = pid / gy;

    const unsigned short* Wt = (sel == 0) ? Wta : (sel == 1) ? Wtb : Wtc;
    const float* bias = (sel == 0) ? ba : (sel == 1) ? bbb : bc;
    unsigned short* outB = (sel == 0) ? oa : (sel == 1) ? ob : oc;

    __shared__ unsigned short As[2][TBM * PIT];   // 2 x 8.5 KB
    __shared__ unsigned short Bs[2][TBN * PIT];   // 2 x 17 KB
    const int t = threadIdx.x;
    const int lane = t & 63;
    const int w = t >> 6, wm = w >> 1, wn = w & 1;
    const int l15 = lane & 15, l4 = lane >> 4;
    const int m0 = by * TBM, n0 = bx * TBN;

    f32x4 acc[2][4];
    #pragma unroll
    for (int i = 0; i < 2; ++i)
        #pragma unroll
        for (int j = 0; j < 4; ++j)
            #pragma unroll
            for (int r = 0; r < 4; ++r) acc[i][j][r] = 0.0f;

    const int ar = t >> 2, aseg = (t & 3) * 16;
    const unsigned short* aG = A + (size_t)(m0 + ar) * K + aseg;
    const int aLo = ar * PIT + aseg;
    const int br = t >> 1, bseg = (t & 1) * 32;
    const unsigned short* bG = Wt + (size_t)(n0 + br) * ldk + bseg;
    const int bLo = br * PIT + bseg;

    u16x8 ra0 = *(const u16x8*)(aG);
    u16x8 ra1 = *(const u16x8*)(aG + 8);
    u16x8 rb0 = *(const u16x8*)(bG);
    u16x8 rb1 = *(const u16x8*)(bG + 8);
    u16x8 rb2 = *(const u16x8*)(bG + 16);
    u16x8 rb3 = *(const u16x8*)(bG + 24);
    *(u16x8*)&As[0][aLo] = ra0; *(u16x8*)&As[0][aLo + 8] = ra1;
    *(u16x8*)&Bs[0][bLo] = rb0; *(u16x8*)&Bs[0][bLo + 8] = rb1;
    *(u16x8*)&Bs[0][bLo + 16] = rb2; *(u16x8*)&Bs[0][bLo + 24] = rb3;
    __syncthreads();

    const int NT = K / TBK;
    for (int kt = 0; kt < NT; ++kt) {
        const int cur = kt & 1;
        const bool more = (kt + 1 < NT);
        if (more) {
            const int k0 = (kt + 1) * TBK;
            ra0 = *(const u16x8*)(aG + k0);
            ra1 = *(const u16x8*)(aG + k0 + 8);
            rb0 = *(const u16x8*)(bG + k0);
            rb1 = *(const u16x8*)(bG + k0 + 8);
            rb2 = *(const u16x8*)(bG + k0 + 16);
            rb3 = *(const u16x8*)(bG + k0 + 24);
        }
        #pragma unroll
        for (int kk = 0; kk < 2; ++kk) {
            bf16x8 af[2], bfr[4];
            #pragma unroll
            for (int mt = 0; mt < 2; ++mt) {
                u16x8 tmp = *(const u16x8*)&As[cur][(wm*32 + mt*16 + l15) * PIT + kk*32 + l4*8];
                af[mt] = __builtin_bit_cast(bf16x8, tmp);
            }
            #pragma unroll
            for (int nt = 0; nt < 4; ++nt) {
                u16x8 tmp = *(const u16x8*)&Bs[cur][(wn*64 + nt*16 + l15) * PIT + kk*32 + l4*8];
                bfr[nt] = __builtin_bit_cast(bf16x8, tmp);
            }
            #pragma unroll
            for (int mt = 0; mt < 2; ++mt)
                #pragma unroll
                for (int nt = 0; nt < 4; ++nt)
                    acc[mt][nt] = __builtin_amdgcn_mfma_f32_16x16x32_bf16(
                        af[mt], bfr[nt], acc[mt][nt], 0, 0, 0);
        }
        if (more) {
            const int nx = cur ^ 1;
            *(u16x8*)&As[nx][aLo] = ra0; *(u16x8*)&As[nx][aLo + 8] = ra1;
            *(u16x8*)&Bs[nx][bLo] = rb0; *(u16x8*)&Bs[nx][bLo + 8] = rb1;
            *(u16x8*)&Bs[nx][bLo + 16] = rb2; *(u16x8*)&Bs[nx][bLo + 24] = rb3;
            __syncthreads();
        }
    }

    #pragma unroll
    for (int mt = 0; mt < 2; ++mt) {
        const int mbase = m0 + wm*32 + mt*16 + l4*4;
        #pragma unroll
        for (int nt = 0; nt < 4; ++nt) {
            const int n = n0 + wn*64 + nt*16 + l15;
            const float bs = (MODE == 4) ? 0.0f : bias[n];
            #pragma unroll
            for (int r = 0; r < 4; ++r) {
                const int m = mbase + r;
                float v = acc[mt][nt][r] + bs;
                if (MODE == 2) v = v / (1.0f + expf(-1.702f * v));
                if (MODE == 1 || MODE == 3) v += bf2f(resid[(size_t)m * N + n]);
                if (MODE == 3)      outF[(size_t)m * N + n] = v;
                else if (MODE == 4) outF[(size_t)m * N + n] += v;
                else                outB[(size_t)m * N + n] = f2bf_n(v);
            }
        }
    }
}

// ---------- MFMA flash attention (round-14, verified) ----------
#define QB2 32
#define AKT 64
#define KROW 72
#define VROW 72
#define PROW 72
#define SBPIT 72

__global__ __launch_bounds__(128) void attn_mfma(const unsigned short* __restrict__ qbuf,
                                                 const unsigned short* __restrict__ kbuf,
                                                 const unsigned short* __restrict__ vbuf,
                                                 const float* __restrict__ attb,
                                                 const int* __restrict__ mask,
                                                 unsigned short* __restrict__ ctx) {
    __shared__ unsigned short Ks[AKT * KROW];
    __shared__ unsigned short Vt[DH * VROW];
    __shared__ unsigned short Pb[2 * 16 * PROW];
    __shared__ unsigned short Sb[QB2 * SBPIT];
    const int t = threadIdx.x;
    const int lane = t & 63;
    const int w = t >> 6;
    const int l15 = lane & 15, l4 = lane >> 4;
    const int q0 = blockIdx.x * QB2;
    const int h = blockIdx.y;
    const int b = blockIdx.z;

    bf16x8 qf[2];
    {
        const unsigned short* qrow = qbuf + ((size_t)(b * SEQ + q0 + w * 16 + l15)) * DM + h * DH;
        u16x8 t0 = *(const u16x8*)(qrow + l4 * 8);
        u16x8 t1 = *(const u16x8*)(qrow + 32 + l4 * 8);
        qf[0] = __builtin_bit_cast(bf16x8, t0);
        qf[1] = __builtin_bit_cast(bf16x8, t1);
    }

    float m[4] = {-1e30f, -1e30f, -1e30f, -1e30f};
    float l[4] = {0.0f, 0.0f, 0.0f, 0.0f};
    f32x4 o[4];
    #pragma unroll
    for (int dt = 0; dt < 4; ++dt)
        #pragma unroll
        for (int r = 0; r < 4; ++r) o[dt][r] = 0.0f;

    unsigned short* Pw = Pb + w * 16 * PROW;

    const int kr = t >> 1, c0 = (t & 1) * 32;
    const int kp = t & 31, vg = t >> 5;

    u16x8 rk0, rk1, rk2, rk3, rv0, rv1, rv2, rv3;
    float4 rb[4];
    int4   rm[4];

#define LOADT(KT) {                                                                     \
    const int kbase = (KT) * AKT;                                                       \
    const unsigned short* gk = kbuf + ((size_t)(b * SEQ + kbase + kr)) * DM + h * DH + c0; \
    rk0 = *(const u16x8*)gk;        rk1 = *(const u16x8*)(gk + 8);                      \
    rk2 = *(const u16x8*)(gk + 16); rk3 = *(const u16x8*)(gk + 24);                     \
    const unsigned short* gv = vbuf + ((size_t)(b * SEQ + kbase + 2 * kp)) * DM + h * DH + vg * 8; \
    rv0 = *(const u16x8*)gv;        rv1 = *(const u16x8*)(gv + DM);                     \
    rv2 = *(const u16x8*)(gv + 32); rv3 = *(const u16x8*)(gv + DM + 32);                \
    const float* bp = attb + (((size_t)(b * NH + h)) * SEQ + (q0 + w * 16)) * SEQ + kbase; \
    const int* mp = mask + ((size_t)(b * SEQ) + q0 + w * 16) * SEQ + kbase;             \
    _Pragma("unroll")                                                                   \
    for (int i = 0; i < 4; ++i) {                                                       \
        const int e = lane + i * 64; const int row = e >> 4, cg = e & 15;               \
        rb[i] = *(const float4*)&bp[(size_t)row * SEQ + cg * 4];                        \
        rm[i] = *(const int4*)&mp[(size_t)row * SEQ + cg * 4];                          \
    } }

#define STORET() {                                                                      \
    unsigned short* s = Ks + kr * KROW + c0;                                            \
    *(u16x8*)s = rk0; *(u16x8*)(s + 8) = rk1;                                           \
    *(u16x8*)(s + 16) = rk2; *(u16x8*)(s + 24) = rk3;                                   \
    unsigned int* vt32 = (unsigned int*)Vt;                                             \
    _Pragma("unroll")                                                                   \
    for (int j = 0; j < 8; ++j) {                                                       \
        vt32[(vg * 8 + j) * (VROW / 2) + kp] =                                          \
            (unsigned int)rv0[j] | ((unsigned int)rv1[j] << 16);                        \
        vt32[((vg + 4) * 8 + j) * (VROW / 2) + kp] =                                    \
            (unsigned int)rv2[j] | ((unsigned int)rv3[j] << 16);                        \
    }                                                                                   \
    _Pragma("unroll")                                                                   \
    for (int i = 0; i < 4; ++i) {                                                       \
        const int e = lane + i * 64; const int row = e >> 4, cg = e & 15;               \
        ushort4 cc;                                                                     \
        cc.x = f2bf_n(rm[i].x ? -8e30f : 8.0f * rb[i].x);                               \
        cc.y = f2bf_n(rm[i].y ? -8e30f : 8.0f * rb[i].y);                               \
        cc.z = f2bf_n(rm[i].z ? -8e30f : 8.0f * rb[i].z);                               \
        cc.w = f2bf_n(rm[i].w ? -8e30f : 8.0f * rb[i].w);                               \
        *(ushort4*)&Sb[(w * 16 + row) * SBPIT + cg * 4] = cc;                           \
    } }

    LOADT(0);
    for (int kt = 0; kt < SEQ / AKT; ++kt) {
        __syncthreads();
        STORET();
        __syncthreads();
        if (kt + 1 < SEQ / AKT) LOADT(kt + 1);

        f32x4 acc[4];
        #pragma unroll
        for (int nt = 0; nt < 4; ++nt)
            #pragma unroll
            for (int r = 0; r < 4; ++r)
                acc[nt][r] = bf2f(Sb[(w * 16 + l4 * 4 + r) * SBPIT + nt * 16 + l15]);

        #pragma unroll
        for (int kk = 0; kk < 2; ++kk) {
            #pragma unroll
            for (int nt = 0; nt < 4; ++nt) {
                u16x8 tmp = *(const u16x8*)(Ks + (nt * 16 + l15) * KROW + kk * 32 + l4 * 8);
                acc[nt] = __builtin_amdgcn_mfma_f32_16x16x32_bf16(
                    qf[kk], __builtin_bit_cast(bf16x8, tmp), acc[nt], 0, 0, 0);
            }
        }

        float pm[4] = {-1e30f, -1e30f, -1e30f, -1e30f};
        #pragma unroll
        for (int nt = 0; nt < 4; ++nt) {
            #pragma unroll
            for (int r = 0; r < 4; ++r) {
                const float sv = acc[nt][r] * 0.125f;
                acc[nt][r] = sv;
                pm[r] = fmaxf(pm[r], sv);
            }
        }
        #pragma unroll
        for (int r = 0; r < 4; ++r) {
            #pragma unroll
            for (int off = 1; off < 16; off <<= 1)
                pm[r] = fmaxf(pm[r], __shfl_xor(pm[r], off));
        }
        float al[4], ps[4];
        #pragma unroll
        for (int r = 0; r < 4; ++r) {
            const float mn = fmaxf(m[r], pm[r]);
            al[r] = __expf(m[r] - mn);
            m[r] = mn;
            ps[r] = 0.0f;
        }
        #pragma unroll
        for (int nt = 0; nt < 4; ++nt) {
            #pragma unroll
            for (int r = 0; r < 4; ++r) {
                const float p = __expf(acc[nt][r] - m[r]);
                acc[nt][r] = p;
                ps[r] += p;
            }
        }
        #pragma unroll
        for (int r = 0; r < 4; ++r) {
            #pragma unroll
            for (int off = 1; off < 16; off <<= 1) ps[r] += __shfl_xor(ps[r], off);
            l[r] = l[r] * al[r] + ps[r];
        }
        #pragma unroll
        for (int dt = 0; dt < 4; ++dt)
            #pragma unroll
            for (int r = 0; r < 4; ++r) o[dt][r] *= al[r];

        #pragma unroll
        for (int nt = 0; nt < 4; ++nt)
            #pragma unroll
            for (int r = 0; r < 4; ++r)
                Pw[(l4 * 4 + r) * PROW + nt * 16 + l15] = f2bf_n(acc[nt][r]);

        #pragma unroll
        for (int ks = 0; ks < 2; ++ks) {
            u16x8 pa = *(const u16x8*)(Pw + l15 * PROW + ks * 32 + l4 * 8);
            #pragma unroll
            for (int dt = 0; dt < 4; ++dt) {
                u16x8 vv = *(const u16x8*)(Vt + (dt * 16 + l15) * VROW + ks * 32 + l4 * 8);
                o[dt] = __builtin_amdgcn_mfma_f32_16x16x32_bf16(
                    __builtin_bit_cast(bf16x8, pa), __builtin_bit_cast(bf16x8, vv),
                    o[dt], 0, 0, 0);
            }
        }
    }

    #pragma unroll
    for (int r = 0; r < 4; ++r) {
        const float inv = 1.0f / l[r];
        const size_t row = (size_t)(b * SEQ + q0 + w * 16 + l4 * 4 + r) * DM + h * DH;
        #pragma unroll
        for (int dt = 0; dt < 4; ++dt)
            ctx[row + dt * 16 + l15] = f2bf_n(o[dt][r] * inv);
    }
#undef LOADT
#undef STORET
}

// ---------------- host launch ----------------
extern "C" void kernel_launch(void* const* d_in, const int* in_sizes, int n_in,
                              void* d_out, int out_size, void* d_ws, size_t ws_size,
                              hipStream_t stream) {
    const float* src  = (const float*)d_in[0];
    const int*   mask = (const int*)d_in[1];
    const int*   ts   = (const int*)d_in[2];
    const float* attb = (const float*)d_in[3];
    const float* Wada = (const float*)d_in[4];
    const float* bada = (const float*)d_in[5];
    const float* Wq   = (const float*)d_in[6];
    const float* bq   = (const float*)d_in[7];
    const float* Wk   = (const float*)d_in[8];
    const float* bk   = (const float*)d_in[9];
    const float* Wv   = (const float*)d_in[10];
    const float* bv   = (const float*)d_in[11];
    const float* Wo   = (const float*)d_in[12];
    const float* bo   = (const float*)d_in[13];
    const float* W1   = (const float*)d_in[14];
    const float* b1   = (const float*)d_in[15];
    const float* W2   = (const float*)d_in[16];
    const float* b2   = (const float*)d_in[17];
    const float* g2   = (const float*)d_in[18];
    const float* bt2  = (const float*)d_in[19];
    float* out = (float*)d_out;

    const size_t MB = 1024 * 1024;
    const size_t NEED = 65536 + 36 * MB;
    const size_t NEED_FULL = 65536 + 52 * MB;
    if (ws_size < NEED) {
        fill0_kernel<<<(size_t)MROWS * DM / 256, 256, 0, stream>>>(out);
        return;
    }
    const bool FULL = (ws_size >= NEED_FULL);

    char* ws = (char*)d_ws;
    float* semb = (float*)(ws + 4096);
    float* ss   = (float*)(ws + 24576);
    char*  base = ws + 65536;
    unsigned short* slotA = (unsigned short*)(base);
    unsigned short* slotB = (unsigned short*)(base + 4 * MB);
    unsigned short* slotC = (unsigned short*)(base + 8 * MB);
    unsigned short* vb   = (unsigned short*)d_out;
    unsigned short* ctxb = (unsigned short*)((char*)d_out + 4 * MB);
    unsigned short* xb = slotA;
    unsigned short* qb = slotB;
    unsigned short* kb = slotC;
    unsigned short* x2 = slotB;
    unsigned short* hb = slotC;
    unsigned short* midc = slotA;
    float* adap = (float*)slotC;

    unsigned short* Wtq = (unsigned short*)(base + 12 * MB);
    unsigned short* Wtk = Wtq + 1024 * 1024;
    unsigned short* Wtv = Wtk + 1024 * 1024;
    unsigned short* Wto = Wtv + 1024 * 1024;
    unsigned short* Wt1 = Wto + 1024 * 1024;               // [4096][1024]
    unsigned short* Wt2 = Wt1 + (size_t)4096 * 1024;       // [1024][4096]
    unsigned short* midF = (unsigned short*)(base + 36 * MB);

    tconv4_kernel<<<dim3(32, 16, 4), 256, 0, stream>>>(Wq, Wk, Wv, Wo, Wtq, Wtk, Wtv, Wto);
    tconv_kernel<<<dim3(128, 16), 256, 0, stream>>>(W1, Wt1, 1024, 4096);
    tconv_kernel<<<dim3(32, 64), 256, 0, stream>>>(W2, Wt2, 4096, 1024);

    semb_kernel<<<4, 256, 0, stream>>>(ts, semb);
    ada_part_kernel<<<dim3(16, 16), 256, 0, stream>>>(semb, Wada, adap);
    ada_red_kernel<<<32, 256, 0, stream>>>(adap, bada, ss);
    adaln_kernel<<<MROWS, 256, 0, stream>>>(src, ss, xb);

    gemm_bt<0><<<dim3(8, 32, 3), 256, 0, stream>>>(xb, Wtq, Wtk, Wtv, bq, bk, bv, nullptr,
                                                   qb, kb, vb, nullptr, MROWS, DM, DM, DM);
    attn_mfma<<<dim3(SEQ / QB2, NH, BATCH), 128, 0, stream>>>(qb, kb, vb, attb, mask, ctxb);
    gemm_bt<1><<<dim3(8, 32), 256, 0, stream>>>(ctxb, Wto, Wto, Wto, bo, bo, bo, xb,
                                                x2, x2, x2, nullptr, MROWS, DM, DM, DM);
    ln2_kernel<<<MROWS, 256, 0, stream>>>(x2, g2, bt2, hb);

    if (FULL) {
        gemm_bt<2><<<dim3(32, 32), 256, 0, stream>>>(hb, Wt1, Wt1, Wt1, b1, b1, b1, nullptr,
                                                     midF, midF, midF, nullptr,
                                                     MROWS, DFF, DM, DM);
        gemm_bt<3><<<dim3(8, 32), 256, 0, stream>>>(midF, Wt2, Wt2, Wt2, b2, b2, b2, x2,
                                                    nullptr, nullptr, nullptr, out,
                                                    MROWS, DM, DFF, DFF);
    } else {
        for (int nc = 0; nc < 4; ++nc) {
            const unsigned short* w1c = Wt1 + (size_t)nc * 1024 * 1024;
            const float* b1c = b1 + nc * 1024;
            gemm_bt<2><<<dim3(8, 32), 256, 0, stream>>>(hb, w1c, w1c, w1c, b1c, b1c, b1c,
                                                        nullptr, midc, midc, midc, nullptr,
                                                        MROWS, DM, DM, DM);
            const unsigned short* w2c = Wt2 + nc * 1024;
            if (nc == 0)
                gemm_bt<3><<<dim3(8, 32), 256, 0, stream>>>(midc, w2c, w2c, w2c, b2, b2, b2,
                                                            x2, nullptr, nullptr, nullptr, out,
                                                            MROWS, DM, DM, DFF);
            else
                gemm_bt<4><<<dim3(8, 32), 256, 0, stream>>>(midc, w2c, w2c, w2c,
                                                            nullptr, nullptr, nullptr, nullptr,
                                                            nullptr, nullptr, nullptr, out,
                                                            MROWS, DM, DM, DFF);
        }
    }
}